// Round 7
// baseline (411.481 us; speedup 1.0000x reference)
//
#include <hip/hip_runtime.h>

// ---------------------------------------------------------------------------
// STFT-Fourier-KAN DGCNN on MI355X.
// R25: af ping-pong NEUTRAL. R26: barrier-free K loop (global B, chunk-major
// ct) NEUTRAL for kan<3>: 81.3us with occupancy 2x (42.6%), conflicts ~0,
// zero barriers -- MfmaUtil still 19%, VALU 38%. Every scheduling lever is
// exhausted; the invariant is the ISSUE RATIO: per wave-chunk ~130cyc of
// VALU/trans af-build feeds only 8 MFMA (40cyc). L3 rebuilds af 16x (16
// col-block families over 1024 cols).
// R27: L3 NT 64->256 (NB=16): 32 MFMA (160cyc) per af-build, recompute
// 16x->4x. 256 blocks = 1/CU exactly; XCD swizzle gives each XCD one
// 256-col B slice (1.15MB, L2-resident); 4 waves/block share 16KB/chunk B
// via L1. acc 128 VGPR, bounds(256,2), peak live ~220 (no spill expected;
// WRITE_SIZE is the tripwire). kan<1>/<2> untouched.
// ---------------------------------------------------------------------------

typedef unsigned short u16;
typedef unsigned int   u32;
typedef unsigned long long u64;
typedef __attribute__((ext_vector_type(8))) _Float16 half8;
typedef __attribute__((ext_vector_type(4))) float f32x4;

__device__ __forceinline__ float bf2f(u16 u) {
  u32 v = ((u32)u) << 16;
  return __uint_as_float(v);
}
__device__ __forceinline__ u16 f2bfr(float f) {  // bf16 round-to-nearest-even
  u32 x = __float_as_uint(f);
  u32 r = x + 0x7FFFu + ((x >> 16) & 1u);
  return (u16)(r >> 16);
}
__device__ __forceinline__ u16 f2h(float f) {    // fp16 RTN bits
  _Float16 h = (_Float16)f;
  u16 r;
  __builtin_memcpy(&r, &h, 2);
  return r;
}
__device__ __forceinline__ float h2f(u16 u) {
  _Float16 h;
  __builtin_memcpy(&h, &u, 2);
  return (float)h;
}
// dtype-dispatched external load (flag wave-uniform -> scalar branch)
__device__ __forceinline__ float ldf(const void* p, size_t i, bool f32) {
  return f32 ? ((const float*)p)[i] : bf2f(((const u16*)p)[i]);
}
__device__ __forceinline__ u64 minu64(u64 a, u64 b) { return a < b ? a : b; }

// ---------------- workspace layout (bytes) ----------------
#define NBR_OFF   ((size_t)0)                       // int32 [163840]       655,360
#define FLAG_OFF  ((size_t)917504)                  // int32 [1]
#define L4P_OFF   (((size_t)(1u << 20)) + 131072)   // f32 [8][15][240]     115,200
#define C1T_OFF   (((size_t)(1u << 20)) + 524288)   // fp16 [2][64][32]       8,192
#define C2T_OFF   (((size_t)(1u << 20)) + 589824)   // fp16 [35][128][32]   286,720
#define C3T_OFF   ((size_t)(2u << 20))              // fp16 [70][1024][32] 4,587,520
#define C4T_OFF   ((size_t)(7u << 20))              // f32  [40][38400]   6,144,000
#define PMAX_OFF  ((size_t)(13u << 20))             // f32 [256][1024]    1,048,576
#define PSUM_OFF  ((size_t)(14u << 20))             // f32 [256][1024]    1,048,576
#define X1_OFF    ((size_t)(15u << 20))             // fp16 [8192][128]   2,097,152
#define H1_OFF    ((size_t)(18u << 20))             // fp16 [163840][64] 20,971,520
// peak ~39 MB

// ---------------- dtype detector -------------------------------------------
__global__ void detect_kernel(const void* __restrict__ pos,
                              int* __restrict__ flag) {
  int t = threadIdx.x;  // 64 threads
  float a = fabsf(((const float*)pos)[t]);
  bool ok = (a > 1.0e-3f && a < 100.0f);
  unsigned long long m = __ballot(ok);
  if (t == 0) *flag = (__popcll(m) >= 32) ? 1 : 0;  // 1 = fp32 externals
}

// ---------------- merged coeff transpose: all four tensors ------------------
// fp16 outputs (c1t/c2t/c3t) CHUNK-MAJOR: dst[c][o][k32], f = c*32+k32.
// c4t keeps the old [o][f] layout (l4_kernel depends on it).
// Angle-major f decode: part=f&1, p=f>>1; p<4*NA: aa=p>>2,g=p&3 ;
// p in [4*NA,5*NA): aa=p-4*NA,g=4. Pad f>=Kt with zeros.
// Block ranges: c1 [0,16) c2 [16,576) c3 [576,9536) c4 [9536,15536).
__global__ void tkan_all_kernel(const void* __restrict__ s1, void* __restrict__ d1,
                                const void* __restrict__ s2, void* __restrict__ d2,
                                const void* __restrict__ s3, void* __restrict__ d3,
                                const void* __restrict__ s4, void* __restrict__ d4,
                                const int* __restrict__ dfl) {
  const int blk = blockIdx.x;
  const void* src; void* dst;
  int dout, nw, W, total, KPAD, outf32, base;
  if (blk < 16)        { src = s1; dst = d1; dout = 64;   nw = 2;  W = 3;
                         total = 64 * 64;     KPAD = 64;    outf32 = 0; base = 0; }
  else if (blk < 576)  { src = s2; dst = d2; dout = 128;  nw = 7;  W = 16;
                         total = 128 * 1120;  KPAD = 1120;  outf32 = 0; base = 16; }
  else if (blk < 9536) { src = s3; dst = d3; dout = 1024; nw = 7;  W = 32;
                         total = 1024 * 2240; KPAD = 2240;  outf32 = 0; base = 576; }
  else                 { src = s4; dst = d4; dout = 40;   nw = 15; W = 256;
                         total = 40 * 38400;  KPAD = 38400; outf32 = 1; base = 9536; }
  int id = (blk - base) * 256 + threadIdx.x;
  if (id >= total) return;
  const bool f32 = (*dfl != 0);
  int o, f;
  if (blk < 9536) {                 // chunk-major: id = (c*dout + o)*32 + k32
    const int k32 = id & 31;
    const int cidx = id >> 5;
    o = cidx % dout;
    f = (cidx / dout) * 32 + k32;
  } else {                          // c4: old row-major [o][f]
    o = id / KPAD; f = id % KPAD;
  }
  int NA = nw * W;
  int Kt = NA * 10;
  float v = 0.f;
  if (f < Kt) {
    int part = f & 1, p = f >> 1;
    int aa, gg;
    if (p < 4 * NA) { aa = p >> 2;      gg = p & 3; }
    else            { aa = p - 4 * NA;  gg = 4;     }
    int i = aa % W, w = aa / W;
    int OS = NA * 5;
    size_t sidx = (size_t)part * (dout * OS) + (size_t)o * OS + w * (W * 5) + i * 5 + gg;
    v = ldf(src, sidx, f32);
  }
  if (outf32) ((float*)dst)[id] = v;
  else        ((u16*)dst)[id] = f2h(v);
}

// ---------------- brute-force kNN: one wave per query -----------------------
__global__ __launch_bounds__(256) void knn_kernel(const void* __restrict__ pos,
                                                  int* __restrict__ nbr,
                                                  const int* __restrict__ dfl) {
  __shared__ float px[1024], py[1024], pz[1024];
  const bool f32 = (*dfl != 0);
  const int t = threadIdx.x;
  const int b = blockIdx.y;
  const int base = b << 10;
  for (int j = t; j < 1024; j += 256) {
    size_t pidx = (size_t)(base + j) * 3;
    px[j] = ldf(pos, pidx, f32);
    py[j] = ldf(pos, pidx + 1, f32);
    pz[j] = ldf(pos, pidx + 2, f32);
  }
  __syncthreads();
  const int wv = t >> 6, lane = t & 63;
  const int q = blockIdx.x * 4 + wv;
  const float qx = px[q], qy = py[q], qz = pz[q];
  u64 key[16];
#pragma unroll
  for (int s = 0; s < 16; ++s) {
    const int j = s * 64 + lane;
    float dx = qx - px[j], dy = qy - py[j], dz = qz - pz[j];
    float d = __fadd_rn(__fadd_rn(__fmul_rn(dx, dx), __fmul_rn(dy, dy)),
                        __fmul_rn(dz, dz));
    key[s] = (j == q) ? ~0ull
                      : ((((u64)__float_as_uint(d)) << 32) | (u32)j);
  }
  const int obase = (base + q) * 20;
  for (int k = 0; k < 20; ++k) {
    u64 m = key[0];
#pragma unroll
    for (int s = 1; s < 16; ++s) m = minu64(m, key[s]);
#pragma unroll
    for (int off = 32; off >= 1; off >>= 1) {
      u32 lo = (u32)m, hi = (u32)(m >> 32);
      lo = __shfl_xor(lo, off, 64);
      hi = __shfl_xor(hi, off, 64);
      m = minu64(m, (((u64)hi) << 32) | lo);
    }
    if (lane == 0) nbr[obase + k] = (int)(u32)m;
#pragma unroll
    for (int s = 0; s < 16; ++s)
      if (key[s] == m) key[s] = ~0ull;  // idx embedded -> unique, safe
  }
}

// ---------------- MFMA KAN layer, barrier-free K loop -----------------------
// B fragments read per-wave directly from L2-resident chunk-major ct
// ([c][DOUTF][32] halves): per (chunk,nb) a wave's 64 lanes cover 1KB
// contiguous. No LDS Bbuf, no ds_write, no __syncthreads in the K loop ->
// waves free-run; compiler pipelines loads across chunks (counted vmcnt).
// PSTH=DIN+4 halves: lane stride -> 16 distinct banks on slab reads.
template <int L>
__global__ __launch_bounds__(256, (L == 1) ? 3 : 2) void kan_kernel(
    const void* __restrict__ in_, const int* __restrict__ nbr,
    const void* __restrict__ pos, const u16* __restrict__ ct,
    const void* __restrict__ bias, void* __restrict__ out_,
    float* __restrict__ pmax, float* __restrict__ psum,
    const int* __restrict__ dfl) {
  constexpr int W    = (L == 1) ? 3  : (L == 2) ? 16  : 32;
  constexpr int S    = (L == 1) ? 3  : (L == 2) ? 8   : 16;
  constexpr int DIN  = (L == 1) ? 6  : (L == 2) ? 64  : 128;
  constexpr int NT   = (L == 1) ? 64 : (L == 2) ? 128 : 256;  // L3: 256 cols
  constexpr int DOUTF = (L == 1) ? 64 : (L == 2) ? 128 : 1024;  // full dout
  constexpr int NW   = (DIN - W) / S + 1;
  constexpr int NA   = NW * W;                      // angles
  constexpr int NPAIR = NA * 5;
  constexpr int S1P  = NA * 4;                      // section-1 pairs (g=1..4)
  constexpr int KROW  = (L == 1) ? 64 : NPAIR * 2;  // padded K (L1 60->64)
  constexpr int NCH   = KROW / 32;                  // L1:2  L2:35  L3:70
  constexpr int NB    = NT / 16;                    // 4 / 8 / 16
  constexpr int RW    = (L == 1) ? 64 : (L == 2) ? 80 : 32;  // rows per wave
  constexpr int MB    = RW / 16;
  constexpr int PSTH  = DIN + 4;                    // slab stride (halves)
  constexpr int LGW   = (W == 16) ? 4 : 5;          // log2(W) for L2/L3

  __shared__ float hamS[(L == 1) ? 1 : W];
  __shared__ float wT1[(L == 1) ? 32 : 1];          // L1 tables (padded K=64)
  __shared__ int   hT1[(L == 1) ? 32 : 1];
  __shared__ u16   slab[(L == 1) ? 2 : 4 * RW * PSTH];
  __shared__ u16   stage1[(L == 1) ? 4 * 64 * 64 : 2];

  const bool f32 = (*dfl != 0);
  const u16* inH = (const u16*)in_;
  const int t = threadIdx.x;
  if constexpr (L == 1) {
    if (t < 32) {
      float wv_ = 0.f; int hx = 0;
      if (t < NPAIR) {                              // angle-major mapping
        int aa, gg;
        if (t < S1P) { aa = t >> 2;   gg = t & 3; }
        else         { aa = t - S1P;  gg = 4;     }
        int i = aa % W;
        float hm = 0.54f - 0.46f * cospif(2.0f * (float)i / (float)(W - 1));
        wv_ = hm * (float)(gg + 1);
        hx = aa;                                    // L1 uses aa directly
      }
      wT1[t] = wv_; hT1[t] = hx;
    }
  } else {
    if (t < W) hamS[t] = 0.54f - 0.46f * cospif(2.0f * (float)t / (float)(W - 1));
  }

  // ---- block index ----
  // L3: 256 blocks = 64 row-tiles x 4 col-tiles. id=8q+r: tile=2q|(r&1),
  // ncol0=(r>>1)*256. Same-XCD blocks (same r) share one 256-col B slice
  // (1.15MB L2-resident) and an even/odd row-tile subset.
  int tile, ncol0;
  if constexpr (L == 3) {
    const int id = blockIdx.x;                      // 256 linear
    tile = ((id >> 3) << 1) | (id & 1);             // [0,64)
    ncol0 = ((id & 7) >> 1) * NT;                   // {0,256,512,768}
  } else {
    tile = blockIdx.x;
    ncol0 = blockIdx.y * NT;
  }
  const int lane = t & 63, wv = t >> 6;
  const int m16 = lane & 15, kb = lane >> 4;
  const int rowbase = tile * (4 * RW) + wv * RW;
  u16* myslab = &slab[(L == 1) ? 0 : wv * RW * PSTH];

  // per-lane B base: chunk c, col nb -> bb0 + c*DOUTF*32 + nb*512 (halves)
  const u16* bb0 = ct + (size_t)(ncol0 + m16) * 32 + kb * 8;

  // ---- stage wave-private fp16 slab (L>=2): uint2 = 4 halves ----
  if constexpr (L >= 2) {
    constexpr int F4R = DIN / 4;
    constexpr int TOT = RW * F4R;
    for (int i = lane; i < TOT; i += 64) {
      const int r = i / F4R, c4 = i % F4R;
      *(uint2*)(myslab + r * PSTH + c4 * 4) =
          *(const uint2*)(inH + (size_t)(rowbase + r) * DIN + c4 * 4);
    }
  }
  __syncthreads();  // covers hamS / wT1 tables (written by wave 0 only)

  f32x4 acc[MB][NB];
#pragma unroll
  for (int mb = 0; mb < MB; ++mb)
#pragma unroll
    for (int nb = 0; nb < NB; ++nb) {
      acc[mb][nb][0] = 0.f; acc[mb][nb][1] = 0.f;
      acc[mb][nb][2] = 0.f; acc[mb][nb][3] = 0.f;
    }

  // ---- A-fragment builder for chunk c (reads slab / pos only) ----
  auto build_af = [&](int c, half8* af) {
    const int pg0 = c * 16 + kb * 4;
    if constexpr (L == 1) {
      float wm[4]; int hx[4]; bool val[4];
#pragma unroll
      for (int u = 0; u < 4; ++u) {
        const int pg = pg0 + u;
        wm[u] = wT1[pg]; hx[u] = hT1[pg]; val[u] = (pg < NPAIR);
      }
#pragma unroll
      for (int mb = 0; mb < MB; ++mb) {
        const int row = rowbase + mb * 16 + m16;
        const int pt = row / 20;
        const int cloud = pt >> 10, ci = pt & 1023;
        const int cb = cloud << 10;
        const int jl = nbr[row];
#pragma unroll
        for (int u = 0; u < 4; ++u) {
          float cs = 0.f, sn = 0.f;
          if (val[u]) {
            const int aa = hx[u];
            float v;
            if (aa < 3) {
              v = ldf(pos, (size_t)(cb + ci) * 3 + aa, f32);
            } else {
              const int cc2 = aa - 3;
              v = ldf(pos, (size_t)(cb + jl) * 3 + cc2, f32) -
                  ldf(pos, (size_t)(cb + ci) * 3 + cc2, f32);
            }
            const float ang = v * wm[u];
            cs = __cosf(ang); sn = __sinf(ang);
          }
          af[mb][2 * u]     = (_Float16)cs;
          af[mb][2 * u + 1] = (_Float16)sn;
        }
      }
    } else if (pg0 < S1P) {
      // section 1: one angle, g=1..4 -> Chebyshev recurrence
      const int aa = pg0 >> 2;
      const int i = aa & (W - 1), w = aa >> LGW;
      const int hidx = S * w + i;
      const float hm = hamS[i];
#pragma unroll
      for (int mb = 0; mb < MB; ++mb) {
        const u16* rp = myslab + (mb * 16 + m16) * PSTH;
        const float th = h2f(rp[hidx]) * hm;
        const float c1 = __cosf(th), s1 = __sinf(th);
        const float tc = 2.0f * c1;
        const float c2 = tc * c1 - 1.0f, s2 = tc * s1;
        const float c3 = tc * c2 - c1,   s3 = tc * s2 - s1;
        const float c4 = tc * c3 - c2,   s4 = tc * s3 - s2;
        af[mb][0] = (_Float16)c1; af[mb][1] = (_Float16)s1;
        af[mb][2] = (_Float16)c2; af[mb][3] = (_Float16)s2;
        af[mb][4] = (_Float16)c3; af[mb][5] = (_Float16)s3;
        af[mb][6] = (_Float16)c4; af[mb][7] = (_Float16)s4;
      }
    } else {
      // section 2: g=5 tail, 4 distinct angles, direct cos/sin
      const int q0 = pg0 - S1P;
      float wm[4]; int hx[4];
#pragma unroll
      for (int u = 0; u < 4; ++u) {
        const int aa = q0 + u;
        const int i = aa & (W - 1), w = aa >> LGW;
        hx[u] = S * w + i;
        wm[u] = hamS[i] * 5.0f;
      }
#pragma unroll
      for (int mb = 0; mb < MB; ++mb) {
        const u16* rp = myslab + (mb * 16 + m16) * PSTH;
#pragma unroll
        for (int u = 0; u < 4; ++u) {
          const float ang = h2f(rp[hx[u]]) * wm[u];
          af[mb][2 * u]     = (_Float16)__cosf(ang);
          af[mb][2 * u + 1] = (_Float16)__sinf(ang);
        }
      }
    }
  };

  // ---- barrier-free K loop ----
  for (int c = 0; c < NCH; ++c) {
    half8 af[MB];
    build_af(c, af);
    const u16* bb = bb0 + (size_t)c * (DOUTF * 32);
#pragma unroll
    for (int nb = 0; nb < NB; ++nb) {
      const half8 bv = *(const half8*)(bb + nb * 512);
#pragma unroll
      for (int mb = 0; mb < MB; ++mb)
        acc[mb][nb] = __builtin_amdgcn_mfma_f32_16x16x32_f16(
            af[mb], bv, acc[mb][nb], 0, 0, 0);
    }
  }

  // ---- fused epilogues (C layout: row=kb*4+r, col=m16 within 16x16) ----
  if constexpr (L == 1) {
    // stage wave C-tile (64 rows x 64 cols fp16) then contiguous copy out
    u16* st = &stage1[wv * 4096];
#pragma unroll
    for (int mb = 0; mb < MB; ++mb)
#pragma unroll
      for (int nb = 0; nb < NB; ++nb) {
        const float bsv = ldf(bias, nb * 16 + m16, f32);
#pragma unroll
        for (int r = 0; r < 4; ++r)
          st[(mb * 16 + kb * 4 + r) * 64 + nb * 16 + m16] =
              f2h(acc[mb][nb][r] + bsv);
      }
    u16* gp = (u16*)out_ + (size_t)rowbase * 64;
    for (int i = lane; i < 512; i += 64)        // 512 x 16B = 8KB
      *(uint4*)(gp + i * 8) = *(const uint4*)&st[i * 8];
  } else if constexpr (L == 2) {
    // C-tile (80x128) -> dead slab (stride PSTH) in two 64-col passes,
    // maxpool over 20 rows each pass, write x1 fp16
    u16* st = myslab;
    const int pbase = tile * 16 + wv * 4;       // 4 points per wave
#pragma unroll
    for (int h = 0; h < 2; ++h) {
#pragma unroll
      for (int mb = 0; mb < MB; ++mb)
#pragma unroll
        for (int nb4 = 0; nb4 < 4; ++nb4) {
          const int nb = h * 4 + nb4;
          const float bsv = ldf(bias, ncol0 + nb * 16 + m16, f32);
#pragma unroll
          for (int r = 0; r < 4; ++r)
            st[(mb * 16 + kb * 4 + r) * PSTH + nb4 * 16 + m16] =
                f2h(acc[mb][nb][r] + bsv);
        }
#pragma unroll
      for (int j = 0; j < 4; ++j) {
        float m = -3.0e38f;
#pragma unroll
        for (int k = 0; k < 20; ++k)
          m = fmaxf(m, h2f(st[(j * 20 + k) * PSTH + lane]));
        ((u16*)out_)[(size_t)(pbase + j) * 128 + ncol0 + h * 64 + lane] = f2h(m);
      }
    }
  } else {
    // in-register max/sum over 32 rows + kb butterfly -> pmax/psum partials
    const int chunk = rowbase >> 5;
#pragma unroll
    for (int nb = 0; nb < NB; ++nb) {
      const int col = ncol0 + nb * 16 + m16;
      const float bsv = ldf(bias, col, f32);
      float m = -3.0e38f, s = 0.f;
#pragma unroll
      for (int mb = 0; mb < MB; ++mb)
#pragma unroll
        for (int r = 0; r < 4; ++r) {
          const float v = acc[mb][nb][r] + bsv;
          m = fmaxf(m, v); s += v;
        }
#pragma unroll
      for (int off = 16; off <= 32; off <<= 1) {
        m = fmaxf(m, __shfl_xor(m, off, 64));
        s += __shfl_xor(s, off, 64);
      }
      if (kb == 0) {
        pmax[(size_t)chunk * 1024 + col] = m;
        psum[(size_t)chunk * 1024 + col] = s;
      }
    }
  }
}

// ---------------- layer 4 partials (seg reduce fused in) --------------------
// c4t GLOBAL layout (angle-major): window w section-1 (g1..4 quads) at
// o*38400 + w*2048 ; g5 tail at o*38400 + 30720 + w*512.
__global__ __launch_bounds__(256) void l4_kernel(const float* __restrict__ pmax,
                                                 const float* __restrict__ psum,
                                                 const float* __restrict__ c4t,
                                                 float* __restrict__ part) {
  __shared__ float F[2560];
  const int t = threadIdx.x;
  const int w = blockIdx.x, b = blockIdx.y;
  // fused segment combine (same reduce order as former seg2)
  const int ch = w * 128 + t;
  float xv;
  if (ch < 1024) {
    float m = -3.0e38f;
    for (int rc = 0; rc < 32; ++rc)
      m = fmaxf(m, pmax[(size_t)(b * 32 + rc) * 1024 + ch]);
    xv = m;
  } else {
    const int cc = ch - 1024;
    float s = 0.f;
    for (int rc = 0; rc < 32; ++rc)
      s += psum[(size_t)(b * 32 + rc) * 1024 + cc];
    xv = s * (1.0f / 1024.0f);
  }
  const float hm = 0.54f - 0.46f * cospif(2.0f * (float)t / 255.0f);
  const float aa = xv * hm;
  const float c1 = __cosf(aa), s1 = __sinf(aa);
  const float tc = 2.0f * c1;
  const float c2 = tc * c1 - 1.0f, s2 = tc * s1;
  const float c3 = tc * c2 - c1,   s3 = tc * s2 - s1;
  const float c4 = tc * c3 - c2,   s4 = tc * s3 - s2;
  const float a5 = aa * 5.0f;
  F[t * 8]     = c1; F[t * 8 + 1] = s1;
  F[t * 8 + 2] = c2; F[t * 8 + 3] = s2;
  F[t * 8 + 4] = c3; F[t * 8 + 5] = s3;
  F[t * 8 + 6] = c4; F[t * 8 + 7] = s4;
  F[2048 + t * 2]     = __cosf(a5);
  F[2048 + t * 2 + 1] = __sinf(a5);
  __syncthreads();
  if (t < 240) {
    const int o = t % 40, s = t / 40;
    const int f0 = s * 432;
    const int f1 = (f0 + 432 < 2560) ? (f0 + 432) : 2560;
    const float* cp1 = c4t + (size_t)o * 38400 + w * 2048;          // sec 1
    const float* cp2 = c4t + (size_t)o * 38400 + 30720 + w * 512;   // g5 tail
    float acc = 0.f;
    for (int f = f0; f < f1; f += 4) {   // 2048 boundary is float4-aligned
      const float* cpf = (f < 2048) ? (cp1 + f) : (cp2 + (f - 2048));
      const float4 cv = *(const float4*)cpf;
      const float4 fa = *(const float4*)&F[f];
      acc += fa.x * cv.x + fa.y * cv.y + fa.z * cv.z + fa.w * cv.w;
    }
    part[((b * 15 + w) * 6 + s) * 40 + o] = acc;
  }
}

__global__ void outred_kernel(const float* __restrict__ part,
                              const void* __restrict__ b4,
                              void* __restrict__ outp,
                              const int* __restrict__ dfl) {
  int t = threadIdx.x;
  if (t >= 320) return;
  const bool f32 = (*dfl != 0);
  int b = t / 40, o = t % 40;
  float s = ldf(b4, o, f32);
  for (int w = 0; w < 15; ++w)
#pragma unroll
    for (int sl = 0; sl < 6; ++sl)
      s += part[((b * 15 + w) * 6 + sl) * 40 + o];
  if (f32) ((float*)outp)[t] = s;
  else     ((u16*)outp)[t] = f2bfr(s);
}

// ---------------------------------------------------------------------------
extern "C" void kernel_launch(void* const* d_in, const int* in_sizes, int n_in,
                              void* d_out, int out_size, void* d_ws,
                              size_t ws_size, hipStream_t stream) {
  (void)in_sizes; (void)n_in; (void)out_size; (void)ws_size;
  const void* pos = d_in[0];
  // d_in[1] = batch (int32) -- clouds are sorted equal-size, used implicitly
  const void* c1 = d_in[2];
  const void* b1 = d_in[3];
  const void* c2 = d_in[4];
  const void* b2 = d_in[5];
  const void* c3 = d_in[6];
  const void* b3 = d_in[7];
  const void* c4 = d_in[8];
  const void* b4 = d_in[9];

  char* ws = (char*)d_ws;
  int* nbr   = (int*)(ws + NBR_OFF);
  int* flag  = (int*)(ws + FLAG_OFF);
  float* l4p = (float*)(ws + L4P_OFF);
  u16* c1t   = (u16*)(ws + C1T_OFF);
  u16* c2t   = (u16*)(ws + C2T_OFF);
  u16* c3t   = (u16*)(ws + C3T_OFF);
  float* c4t = (float*)(ws + C4T_OFF);
  float* pmax = (float*)(ws + PMAX_OFF);
  float* psum = (float*)(ws + PSUM_OFF);
  u16* x1    = (u16*)(ws + X1_OFF);
  u16* h1    = (u16*)(ws + H1_OFF);

  detect_kernel<<<1, 64, 0, stream>>>(pos, flag);

  tkan_all_kernel<<<15536, 256, 0, stream>>>(c1, c1t, c2, c2t, c3, c3t,
                                             c4, c4t, flag);

  knn_kernel<<<dim3(256, 8), 256, 0, stream>>>(pos, nbr, flag);

  // L1: 640 blocks x 256 rows, NT=DOUT=64
  kan_kernel<1><<<640, 256, 0, stream>>>(nullptr, nbr, pos, c1t, b1, h1,
                                         nullptr, nullptr, flag);
  // L2 fused maxpool: 512 blocks x 320 rows (16 points), NT=128, no barriers
  kan_kernel<2><<<dim3(512), 256, 0, stream>>>(h1, nullptr, nullptr, c2t,
                                               b2, x1, nullptr, nullptr, flag);
  // L3 fused segment partials: 256 blocks (64 row-tiles x 4 col-tiles of
  // NT=256), XCD-swizzled inside, 1 block/CU
  kan_kernel<3><<<256, 256, 0, stream>>>(x1, nullptr, nullptr, c3t,
                                         b3, nullptr, pmax, psum, flag);

  l4_kernel<<<dim3(15, 8), 256, 0, stream>>>(pmax, psum, c4t, l4p);
  outred_kernel<<<1, 320, 0, stream>>>(l4p, b4, d_out, flag);
}

// Round 8
// 384.549 us; speedup vs baseline: 1.0700x; 1.0700x over previous
//
#include <hip/hip_runtime.h>

// ---------------------------------------------------------------------------
// STFT-Fourier-KAN DGCNN on MI355X.
// R26: barrier-free K loop, chunk-major ct. kan<3> 81us, MfmaUtil 19% --
// issue-ratio bound (af-build VALU : MFMA ~= 3:1 at NB=8, 16x recompute).
// R27: NT=256/RW=32/1 block-per-CU REGRESSED 81->169us: VGPR_Count=84 --
// acc(128, AGPR) left too few arch VGPRs to pipeline the 16 bv loads ->
// serialized at full L2 latency (~5.8Kcyc/chunk = 16x300cyc), and 1
// wave/SIMD gave zero TLP. Both pipes <9%.
// R28: keep NB=16 (the ratio lever), halve acc: RW 32->16 (MB=1, acc=64)
// -> ~64 freed VGPRs for load pipelining; grid 512 = 2 blocks/CU (8
// waves/CU TLP). RW=16 breaks 32-row pmax chunking -> epilogue LDS
// pair-combine: wave stages 16-row partials in its dead slab region,
// one barrier, even waves merge with wv+1 -> 32-row chunk write.
// kan<1>/<2> untouched.
// ---------------------------------------------------------------------------

typedef unsigned short u16;
typedef unsigned int   u32;
typedef unsigned long long u64;
typedef __attribute__((ext_vector_type(8))) _Float16 half8;
typedef __attribute__((ext_vector_type(4))) float f32x4;

__device__ __forceinline__ float bf2f(u16 u) {
  u32 v = ((u32)u) << 16;
  return __uint_as_float(v);
}
__device__ __forceinline__ u16 f2bfr(float f) {  // bf16 round-to-nearest-even
  u32 x = __float_as_uint(f);
  u32 r = x + 0x7FFFu + ((x >> 16) & 1u);
  return (u16)(r >> 16);
}
__device__ __forceinline__ u16 f2h(float f) {    // fp16 RTN bits
  _Float16 h = (_Float16)f;
  u16 r;
  __builtin_memcpy(&r, &h, 2);
  return r;
}
__device__ __forceinline__ float h2f(u16 u) {
  _Float16 h;
  __builtin_memcpy(&h, &u, 2);
  return (float)h;
}
// dtype-dispatched external load (flag wave-uniform -> scalar branch)
__device__ __forceinline__ float ldf(const void* p, size_t i, bool f32) {
  return f32 ? ((const float*)p)[i] : bf2f(((const u16*)p)[i]);
}
__device__ __forceinline__ u64 minu64(u64 a, u64 b) { return a < b ? a : b; }

// ---------------- workspace layout (bytes) ----------------
#define NBR_OFF   ((size_t)0)                       // int32 [163840]       655,360
#define FLAG_OFF  ((size_t)917504)                  // int32 [1]
#define L4P_OFF   (((size_t)(1u << 20)) + 131072)   // f32 [8][15][240]     115,200
#define C1T_OFF   (((size_t)(1u << 20)) + 524288)   // fp16 [2][64][32]       8,192
#define C2T_OFF   (((size_t)(1u << 20)) + 589824)   // fp16 [35][128][32]   286,720
#define C3T_OFF   ((size_t)(2u << 20))              // fp16 [70][1024][32] 4,587,520
#define C4T_OFF   ((size_t)(7u << 20))              // f32  [40][38400]   6,144,000
#define PMAX_OFF  ((size_t)(13u << 20))             // f32 [256][1024]    1,048,576
#define PSUM_OFF  ((size_t)(14u << 20))             // f32 [256][1024]    1,048,576
#define X1_OFF    ((size_t)(15u << 20))             // fp16 [8192][128]   2,097,152
#define H1_OFF    ((size_t)(18u << 20))             // fp16 [163840][64] 20,971,520
// peak ~39 MB

// ---------------- dtype detector -------------------------------------------
__global__ void detect_kernel(const void* __restrict__ pos,
                              int* __restrict__ flag) {
  int t = threadIdx.x;  // 64 threads
  float a = fabsf(((const float*)pos)[t]);
  bool ok = (a > 1.0e-3f && a < 100.0f);
  unsigned long long m = __ballot(ok);
  if (t == 0) *flag = (__popcll(m) >= 32) ? 1 : 0;  // 1 = fp32 externals
}

// ---------------- merged coeff transpose: all four tensors ------------------
// fp16 outputs (c1t/c2t/c3t) CHUNK-MAJOR: dst[c][o][k32], f = c*32+k32.
// c4t keeps the old [o][f] layout (l4_kernel depends on it).
// Angle-major f decode: part=f&1, p=f>>1; p<4*NA: aa=p>>2,g=p&3 ;
// p in [4*NA,5*NA): aa=p-4*NA,g=4. Pad f>=Kt with zeros.
// Block ranges: c1 [0,16) c2 [16,576) c3 [576,9536) c4 [9536,15536).
__global__ void tkan_all_kernel(const void* __restrict__ s1, void* __restrict__ d1,
                                const void* __restrict__ s2, void* __restrict__ d2,
                                const void* __restrict__ s3, void* __restrict__ d3,
                                const void* __restrict__ s4, void* __restrict__ d4,
                                const int* __restrict__ dfl) {
  const int blk = blockIdx.x;
  const void* src; void* dst;
  int dout, nw, W, total, KPAD, outf32, base;
  if (blk < 16)        { src = s1; dst = d1; dout = 64;   nw = 2;  W = 3;
                         total = 64 * 64;     KPAD = 64;    outf32 = 0; base = 0; }
  else if (blk < 576)  { src = s2; dst = d2; dout = 128;  nw = 7;  W = 16;
                         total = 128 * 1120;  KPAD = 1120;  outf32 = 0; base = 16; }
  else if (blk < 9536) { src = s3; dst = d3; dout = 1024; nw = 7;  W = 32;
                         total = 1024 * 2240; KPAD = 2240;  outf32 = 0; base = 576; }
  else                 { src = s4; dst = d4; dout = 40;   nw = 15; W = 256;
                         total = 40 * 38400;  KPAD = 38400; outf32 = 1; base = 9536; }
  int id = (blk - base) * 256 + threadIdx.x;
  if (id >= total) return;
  const bool f32 = (*dfl != 0);
  int o, f;
  if (blk < 9536) {                 // chunk-major: id = (c*dout + o)*32 + k32
    const int k32 = id & 31;
    const int cidx = id >> 5;
    o = cidx % dout;
    f = (cidx / dout) * 32 + k32;
  } else {                          // c4: old row-major [o][f]
    o = id / KPAD; f = id % KPAD;
  }
  int NA = nw * W;
  int Kt = NA * 10;
  float v = 0.f;
  if (f < Kt) {
    int part = f & 1, p = f >> 1;
    int aa, gg;
    if (p < 4 * NA) { aa = p >> 2;      gg = p & 3; }
    else            { aa = p - 4 * NA;  gg = 4;     }
    int i = aa % W, w = aa / W;
    int OS = NA * 5;
    size_t sidx = (size_t)part * (dout * OS) + (size_t)o * OS + w * (W * 5) + i * 5 + gg;
    v = ldf(src, sidx, f32);
  }
  if (outf32) ((float*)dst)[id] = v;
  else        ((u16*)dst)[id] = f2h(v);
}

// ---------------- brute-force kNN: one wave per query -----------------------
__global__ __launch_bounds__(256) void knn_kernel(const void* __restrict__ pos,
                                                  int* __restrict__ nbr,
                                                  const int* __restrict__ dfl) {
  __shared__ float px[1024], py[1024], pz[1024];
  const bool f32 = (*dfl != 0);
  const int t = threadIdx.x;
  const int b = blockIdx.y;
  const int base = b << 10;
  for (int j = t; j < 1024; j += 256) {
    size_t pidx = (size_t)(base + j) * 3;
    px[j] = ldf(pos, pidx, f32);
    py[j] = ldf(pos, pidx + 1, f32);
    pz[j] = ldf(pos, pidx + 2, f32);
  }
  __syncthreads();
  const int wv = t >> 6, lane = t & 63;
  const int q = blockIdx.x * 4 + wv;
  const float qx = px[q], qy = py[q], qz = pz[q];
  u64 key[16];
#pragma unroll
  for (int s = 0; s < 16; ++s) {
    const int j = s * 64 + lane;
    float dx = qx - px[j], dy = qy - py[j], dz = qz - pz[j];
    float d = __fadd_rn(__fadd_rn(__fmul_rn(dx, dx), __fmul_rn(dy, dy)),
                        __fmul_rn(dz, dz));
    key[s] = (j == q) ? ~0ull
                      : ((((u64)__float_as_uint(d)) << 32) | (u32)j);
  }
  const int obase = (base + q) * 20;
  for (int k = 0; k < 20; ++k) {
    u64 m = key[0];
#pragma unroll
    for (int s = 1; s < 16; ++s) m = minu64(m, key[s]);
#pragma unroll
    for (int off = 32; off >= 1; off >>= 1) {
      u32 lo = (u32)m, hi = (u32)(m >> 32);
      lo = __shfl_xor(lo, off, 64);
      hi = __shfl_xor(hi, off, 64);
      m = minu64(m, (((u64)hi) << 32) | lo);
    }
    if (lane == 0) nbr[obase + k] = (int)(u32)m;
#pragma unroll
    for (int s = 0; s < 16; ++s)
      if (key[s] == m) key[s] = ~0ull;  // idx embedded -> unique, safe
  }
}

// ---------------- MFMA KAN layer, barrier-free K loop -----------------------
// B fragments read per-wave directly from L2-resident chunk-major ct
// ([c][DOUTF][32] halves): per (chunk,nb) a wave's 64 lanes cover 1KB
// contiguous. No LDS Bbuf, no ds_write, no __syncthreads in the K loop ->
// waves free-run; compiler pipelines loads across chunks (counted vmcnt).
// PSTH=DIN+4 halves: lane stride -> 16 distinct banks on slab reads.
template <int L>
__global__ __launch_bounds__(256, (L == 1) ? 3 : 2) void kan_kernel(
    const void* __restrict__ in_, const int* __restrict__ nbr,
    const void* __restrict__ pos, const u16* __restrict__ ct,
    const void* __restrict__ bias, void* __restrict__ out_,
    float* __restrict__ pmax, float* __restrict__ psum,
    const int* __restrict__ dfl) {
  constexpr int W    = (L == 1) ? 3  : (L == 2) ? 16  : 32;
  constexpr int S    = (L == 1) ? 3  : (L == 2) ? 8   : 16;
  constexpr int DIN  = (L == 1) ? 6  : (L == 2) ? 64  : 128;
  constexpr int NT   = (L == 1) ? 64 : (L == 2) ? 128 : 256;  // L3: 256 cols
  constexpr int DOUTF = (L == 1) ? 64 : (L == 2) ? 128 : 1024;  // full dout
  constexpr int NW   = (DIN - W) / S + 1;
  constexpr int NA   = NW * W;                      // angles
  constexpr int NPAIR = NA * 5;
  constexpr int S1P  = NA * 4;                      // section-1 pairs (g=1..4)
  constexpr int KROW  = (L == 1) ? 64 : NPAIR * 2;  // padded K (L1 60->64)
  constexpr int NCH   = KROW / 32;                  // L1:2  L2:35  L3:70
  constexpr int NB    = NT / 16;                    // 4 / 8 / 16
  constexpr int RW    = (L == 1) ? 64 : (L == 2) ? 80 : 16;  // rows per wave
  constexpr int MB    = RW / 16;                    // L3: 1 (acc=64 regs)
  constexpr int PSTH  = DIN + 4;                    // slab stride (halves)
  constexpr int LGW   = (W == 16) ? 4 : 5;          // log2(W) for L2/L3

  __shared__ float hamS[(L == 1) ? 1 : W];
  __shared__ float wT1[(L == 1) ? 32 : 1];          // L1 tables (padded K=64)
  __shared__ int   hT1[(L == 1) ? 32 : 1];
  __shared__ u16   slab[(L == 1) ? 2 : 4 * RW * PSTH];
  __shared__ u16   stage1[(L == 1) ? 4 * 64 * 64 : 2];

  const bool f32 = (*dfl != 0);
  const u16* inH = (const u16*)in_;
  const int t = threadIdx.x;
  if constexpr (L == 1) {
    if (t < 32) {
      float wv_ = 0.f; int hx = 0;
      if (t < NPAIR) {                              // angle-major mapping
        int aa, gg;
        if (t < S1P) { aa = t >> 2;   gg = t & 3; }
        else         { aa = t - S1P;  gg = 4;     }
        int i = aa % W;
        float hm = 0.54f - 0.46f * cospif(2.0f * (float)i / (float)(W - 1));
        wv_ = hm * (float)(gg + 1);
        hx = aa;                                    // L1 uses aa directly
      }
      wT1[t] = wv_; hT1[t] = hx;
    }
  } else {
    if (t < W) hamS[t] = 0.54f - 0.46f * cospif(2.0f * (float)t / (float)(W - 1));
  }

  // ---- block index ----
  // L3: 512 blocks = 128 row-tiles (64 rows each) x 4 col-tiles (NT=256).
  // id=8q+r: tile=2q|(r&1), ncol0=(r>>1)*256 -> XCD pairs share a col slice
  // (1.15MB, L2-resident).
  int tile, ncol0;
  if constexpr (L == 3) {
    const int id = blockIdx.x;                      // 512 linear
    tile = ((id >> 3) << 1) | (id & 1);             // [0,128)
    ncol0 = ((id & 7) >> 1) * NT;                   // {0,256,512,768}
  } else {
    tile = blockIdx.x;
    ncol0 = blockIdx.y * NT;
  }
  const int lane = t & 63, wv = t >> 6;
  const int m16 = lane & 15, kb = lane >> 4;
  const int rowbase = tile * (4 * RW) + wv * RW;
  u16* myslab = &slab[(L == 1) ? 0 : wv * RW * PSTH];

  // per-lane B base: chunk c, col nb -> bb0 + c*DOUTF*32 + nb*512 (halves)
  const u16* bb0 = ct + (size_t)(ncol0 + m16) * 32 + kb * 8;

  // ---- stage wave-private fp16 slab (L>=2): uint2 = 4 halves ----
  if constexpr (L >= 2) {
    constexpr int F4R = DIN / 4;
    constexpr int TOT = RW * F4R;
    for (int i = lane; i < TOT; i += 64) {
      const int r = i / F4R, c4 = i % F4R;
      *(uint2*)(myslab + r * PSTH + c4 * 4) =
          *(const uint2*)(inH + (size_t)(rowbase + r) * DIN + c4 * 4);
    }
  }
  __syncthreads();  // covers hamS / wT1 tables (written by wave 0 only)

  f32x4 acc[MB][NB];
#pragma unroll
  for (int mb = 0; mb < MB; ++mb)
#pragma unroll
    for (int nb = 0; nb < NB; ++nb) {
      acc[mb][nb][0] = 0.f; acc[mb][nb][1] = 0.f;
      acc[mb][nb][2] = 0.f; acc[mb][nb][3] = 0.f;
    }

  // ---- A-fragment builder for chunk c (reads slab / pos only) ----
  auto build_af = [&](int c, half8* af) {
    const int pg0 = c * 16 + kb * 4;
    if constexpr (L == 1) {
      float wm[4]; int hx[4]; bool val[4];
#pragma unroll
      for (int u = 0; u < 4; ++u) {
        const int pg = pg0 + u;
        wm[u] = wT1[pg]; hx[u] = hT1[pg]; val[u] = (pg < NPAIR);
      }
#pragma unroll
      for (int mb = 0; mb < MB; ++mb) {
        const int row = rowbase + mb * 16 + m16;
        const int pt = row / 20;
        const int cloud = pt >> 10, ci = pt & 1023;
        const int cb = cloud << 10;
        const int jl = nbr[row];
#pragma unroll
        for (int u = 0; u < 4; ++u) {
          float cs = 0.f, sn = 0.f;
          if (val[u]) {
            const int aa = hx[u];
            float v;
            if (aa < 3) {
              v = ldf(pos, (size_t)(cb + ci) * 3 + aa, f32);
            } else {
              const int cc2 = aa - 3;
              v = ldf(pos, (size_t)(cb + jl) * 3 + cc2, f32) -
                  ldf(pos, (size_t)(cb + ci) * 3 + cc2, f32);
            }
            const float ang = v * wm[u];
            cs = __cosf(ang); sn = __sinf(ang);
          }
          af[mb][2 * u]     = (_Float16)cs;
          af[mb][2 * u + 1] = (_Float16)sn;
        }
      }
    } else if (pg0 < S1P) {
      // section 1: one angle, g=1..4 -> Chebyshev recurrence
      const int aa = pg0 >> 2;
      const int i = aa & (W - 1), w = aa >> LGW;
      const int hidx = S * w + i;
      const float hm = hamS[i];
#pragma unroll
      for (int mb = 0; mb < MB; ++mb) {
        const u16* rp = myslab + (mb * 16 + m16) * PSTH;
        const float th = h2f(rp[hidx]) * hm;
        const float c1 = __cosf(th), s1 = __sinf(th);
        const float tc = 2.0f * c1;
        const float c2 = tc * c1 - 1.0f, s2 = tc * s1;
        const float c3 = tc * c2 - c1,   s3 = tc * s2 - s1;
        const float c4 = tc * c3 - c2,   s4 = tc * s3 - s2;
        af[mb][0] = (_Float16)c1; af[mb][1] = (_Float16)s1;
        af[mb][2] = (_Float16)c2; af[mb][3] = (_Float16)s2;
        af[mb][4] = (_Float16)c3; af[mb][5] = (_Float16)s3;
        af[mb][6] = (_Float16)c4; af[mb][7] = (_Float16)s4;
      }
    } else {
      // section 2: g=5 tail, 4 distinct angles, direct cos/sin
      const int q0 = pg0 - S1P;
      float wm[4]; int hx[4];
#pragma unroll
      for (int u = 0; u < 4; ++u) {
        const int aa = q0 + u;
        const int i = aa & (W - 1), w = aa >> LGW;
        hx[u] = S * w + i;
        wm[u] = hamS[i] * 5.0f;
      }
#pragma unroll
      for (int mb = 0; mb < MB; ++mb) {
        const u16* rp = myslab + (mb * 16 + m16) * PSTH;
#pragma unroll
        for (int u = 0; u < 4; ++u) {
          const float ang = h2f(rp[hx[u]]) * wm[u];
          af[mb][2 * u]     = (_Float16)__cosf(ang);
          af[mb][2 * u + 1] = (_Float16)__sinf(ang);
        }
      }
    }
  };

  // ---- barrier-free K loop ----
  for (int c = 0; c < NCH; ++c) {
    half8 af[MB];
    build_af(c, af);
    const u16* bb = bb0 + (size_t)c * (DOUTF * 32);
#pragma unroll
    for (int nb = 0; nb < NB; ++nb) {
      const half8 bv = *(const half8*)(bb + nb * 512);
#pragma unroll
      for (int mb = 0; mb < MB; ++mb)
        acc[mb][nb] = __builtin_amdgcn_mfma_f32_16x16x32_f16(
            af[mb], bv, acc[mb][nb], 0, 0, 0);
    }
  }

  // ---- fused epilogues (C layout: row=kb*4+r, col=m16 within 16x16) ----
  if constexpr (L == 1) {
    // stage wave C-tile (64 rows x 64 cols fp16) then contiguous copy out
    u16* st = &stage1[wv * 4096];
#pragma unroll
    for (int mb = 0; mb < MB; ++mb)
#pragma unroll
      for (int nb = 0; nb < NB; ++nb) {
        const float bsv = ldf(bias, nb * 16 + m16, f32);
#pragma unroll
        for (int r = 0; r < 4; ++r)
          st[(mb * 16 + kb * 4 + r) * 64 + nb * 16 + m16] =
              f2h(acc[mb][nb][r] + bsv);
      }
    u16* gp = (u16*)out_ + (size_t)rowbase * 64;
    for (int i = lane; i < 512; i += 64)        // 512 x 16B = 8KB
      *(uint4*)(gp + i * 8) = *(const uint4*)&st[i * 8];
  } else if constexpr (L == 2) {
    // C-tile (80x128) -> dead slab (stride PSTH) in two 64-col passes,
    // maxpool over 20 rows each pass, write x1 fp16
    u16* st = myslab;
    const int pbase = tile * 16 + wv * 4;       // 4 points per wave
#pragma unroll
    for (int h = 0; h < 2; ++h) {
#pragma unroll
      for (int mb = 0; mb < MB; ++mb)
#pragma unroll
        for (int nb4 = 0; nb4 < 4; ++nb4) {
          const int nb = h * 4 + nb4;
          const float bsv = ldf(bias, ncol0 + nb * 16 + m16, f32);
#pragma unroll
          for (int r = 0; r < 4; ++r)
            st[(mb * 16 + kb * 4 + r) * PSTH + nb4 * 16 + m16] =
                f2h(acc[mb][nb][r] + bsv);
        }
#pragma unroll
      for (int j = 0; j < 4; ++j) {
        float m = -3.0e38f;
#pragma unroll
        for (int k = 0; k < 20; ++k)
          m = fmaxf(m, h2f(st[(j * 20 + k) * PSTH + lane]));
        ((u16*)out_)[(size_t)(pbase + j) * 128 + ncol0 + h * 64 + lane] = f2h(m);
      }
    }
  } else {
    // 16-row per-wave partials -> wave-private slab floats -> barrier ->
    // even waves merge with wv+1 into the 32-row pmax/psum chunk.
    float* mf = (float*)myslab;                 // 256 floats (1KB <= 4.2KB)
    float* sf = mf + 256;
#pragma unroll
    for (int nb = 0; nb < NB; ++nb) {
      const int col = ncol0 + nb * 16 + m16;
      const float bsv = ldf(bias, col, f32);
      float m = -3.0e38f, s = 0.f;
#pragma unroll
      for (int mb = 0; mb < MB; ++mb)
#pragma unroll
        for (int r = 0; r < 4; ++r) {
          const float v = acc[mb][nb][r] + bsv;
          m = fmaxf(m, v); s += v;
        }
#pragma unroll
      for (int off = 16; off <= 32; off <<= 1) {
        m = fmaxf(m, __shfl_xor(m, off, 64));
        s += __shfl_xor(s, off, 64);
      }
      mf[nb * 16 + m16] = m;    // kb groups write identical values (benign)
      sf[nb * 16 + m16] = s;
    }
    __syncthreads();
    if ((wv & 1) == 0) {
      const float* mf2 = (const float*)(slab + (wv + 1) * RW * PSTH);
      const float* sf2 = mf2 + 256;
      const int chunk = tile * 2 + (wv >> 1);   // 32-row chunk index [0,256)
      for (int i = lane; i < 256; i += 64) {
        pmax[(size_t)chunk * 1024 + ncol0 + i] = fmaxf(mf[i], mf2[i]);
        psum[(size_t)chunk * 1024 + ncol0 + i] = sf[i] + sf2[i];
      }
    }
  }
}

// ---------------- layer 4 partials (seg reduce fused in) --------------------
// c4t GLOBAL layout (angle-major): window w section-1 (g1..4 quads) at
// o*38400 + w*2048 ; g5 tail at o*38400 + 30720 + w*512.
__global__ __launch_bounds__(256) void l4_kernel(const float* __restrict__ pmax,
                                                 const float* __restrict__ psum,
                                                 const float* __restrict__ c4t,
                                                 float* __restrict__ part) {
  __shared__ float F[2560];
  const int t = threadIdx.x;
  const int w = blockIdx.x, b = blockIdx.y;
  // fused segment combine (same reduce order as former seg2)
  const int ch = w * 128 + t;
  float xv;
  if (ch < 1024) {
    float m = -3.0e38f;
    for (int rc = 0; rc < 32; ++rc)
      m = fmaxf(m, pmax[(size_t)(b * 32 + rc) * 1024 + ch]);
    xv = m;
  } else {
    const int cc = ch - 1024;
    float s = 0.f;
    for (int rc = 0; rc < 32; ++rc)
      s += psum[(size_t)(b * 32 + rc) * 1024 + cc];
    xv = s * (1.0f / 1024.0f);
  }
  const float hm = 0.54f - 0.46f * cospif(2.0f * (float)t / 255.0f);
  const float aa = xv * hm;
  const float c1 = __cosf(aa), s1 = __sinf(aa);
  const float tc = 2.0f * c1;
  const float c2 = tc * c1 - 1.0f, s2 = tc * s1;
  const float c3 = tc * c2 - c1,   s3 = tc * s2 - s1;
  const float c4 = tc * c3 - c2,   s4 = tc * s3 - s2;
  const float a5 = aa * 5.0f;
  F[t * 8]     = c1; F[t * 8 + 1] = s1;
  F[t * 8 + 2] = c2; F[t * 8 + 3] = s2;
  F[t * 8 + 4] = c3; F[t * 8 + 5] = s3;
  F[t * 8 + 6] = c4; F[t * 8 + 7] = s4;
  F[2048 + t * 2]     = __cosf(a5);
  F[2048 + t * 2 + 1] = __sinf(a5);
  __syncthreads();
  if (t < 240) {
    const int o = t % 40, s = t / 40;
    const int f0 = s * 432;
    const int f1 = (f0 + 432 < 2560) ? (f0 + 432) : 2560;
    const float* cp1 = c4t + (size_t)o * 38400 + w * 2048;          // sec 1
    const float* cp2 = c4t + (size_t)o * 38400 + 30720 + w * 512;   // g5 tail
    float acc = 0.f;
    for (int f = f0; f < f1; f += 4) {   // 2048 boundary is float4-aligned
      const float* cpf = (f < 2048) ? (cp1 + f) : (cp2 + (f - 2048));
      const float4 cv = *(const float4*)cpf;
      const float4 fa = *(const float4*)&F[f];
      acc += fa.x * cv.x + fa.y * cv.y + fa.z * cv.z + fa.w * cv.w;
    }
    part[((b * 15 + w) * 6 + s) * 40 + o] = acc;
  }
}

__global__ void outred_kernel(const float* __restrict__ part,
                              const void* __restrict__ b4,
                              void* __restrict__ outp,
                              const int* __restrict__ dfl) {
  int t = threadIdx.x;
  if (t >= 320) return;
  const bool f32 = (*dfl != 0);
  int b = t / 40, o = t % 40;
  float s = ldf(b4, o, f32);
  for (int w = 0; w < 15; ++w)
#pragma unroll
    for (int sl = 0; sl < 6; ++sl)
      s += part[((b * 15 + w) * 6 + sl) * 40 + o];
  if (f32) ((float*)outp)[t] = s;
  else     ((u16*)outp)[t] = f2bfr(s);
}

// ---------------------------------------------------------------------------
extern "C" void kernel_launch(void* const* d_in, const int* in_sizes, int n_in,
                              void* d_out, int out_size, void* d_ws,
                              size_t ws_size, hipStream_t stream) {
  (void)in_sizes; (void)n_in; (void)out_size; (void)ws_size;
  const void* pos = d_in[0];
  // d_in[1] = batch (int32) -- clouds are sorted equal-size, used implicitly
  const void* c1 = d_in[2];
  const void* b1 = d_in[3];
  const void* c2 = d_in[4];
  const void* b2 = d_in[5];
  const void* c3 = d_in[6];
  const void* b3 = d_in[7];
  const void* c4 = d_in[8];
  const void* b4 = d_in[9];

  char* ws = (char*)d_ws;
  int* nbr   = (int*)(ws + NBR_OFF);
  int* flag  = (int*)(ws + FLAG_OFF);
  float* l4p = (float*)(ws + L4P_OFF);
  u16* c1t   = (u16*)(ws + C1T_OFF);
  u16* c2t   = (u16*)(ws + C2T_OFF);
  u16* c3t   = (u16*)(ws + C3T_OFF);
  float* c4t = (float*)(ws + C4T_OFF);
  float* pmax = (float*)(ws + PMAX_OFF);
  float* psum = (float*)(ws + PSUM_OFF);
  u16* x1    = (u16*)(ws + X1_OFF);
  u16* h1    = (u16*)(ws + H1_OFF);

  detect_kernel<<<1, 64, 0, stream>>>(pos, flag);

  tkan_all_kernel<<<15536, 256, 0, stream>>>(c1, c1t, c2, c2t, c3, c3t,
                                             c4, c4t, flag);

  knn_kernel<<<dim3(256, 8), 256, 0, stream>>>(pos, nbr, flag);

  // L1: 640 blocks x 256 rows, NT=DOUT=64
  kan_kernel<1><<<640, 256, 0, stream>>>(nullptr, nbr, pos, c1t, b1, h1,
                                         nullptr, nullptr, flag);
  // L2 fused maxpool: 512 blocks x 320 rows (16 points), NT=128, no barriers
  kan_kernel<2><<<dim3(512), 256, 0, stream>>>(h1, nullptr, nullptr, c2t,
                                               b2, x1, nullptr, nullptr, flag);
  // L3 fused segment partials: 512 blocks (128 row-tiles x 4 col-tiles of
  // NT=256, RW=16), XCD-swizzled inside, 2 blocks/CU
  kan_kernel<3><<<512, 256, 0, stream>>>(x1, nullptr, nullptr, c3t,
                                         b3, nullptr, pmax, psum, flag);

  l4_kernel<<<dim3(15, 8), 256, 0, stream>>>(pmax, psum, c4t, l4p);
  outred_kernel<<<1, 320, 0, stream>>>(l4p, b4, d_out, flag);
}

// Round 10
// 293.490 us; speedup vs baseline: 1.4020x; 1.3103x over previous
//
#include <hip/hip_runtime.h>

// ---------------------------------------------------------------------------
// STFT-Fourier-KAN DGCNN on MI355X.
// R26-R28 post-mortem: three structural variants of kan<3> (barrier-free
// global-B NB=8/16, RW=32/16) all lost to the LDS-staged R25 shape:
// barrier-free quadruples L2 B-traffic (staging = dedup) and the compiler
// serializes the per-chunk B loads at ~300cyc L2 latency (R28: VGPR=52,
// 5Kcyc/chunk = 16x300). R25 (301.0us total; kan<2> 78.4, kan<3> 78.1)
// remains best: LDS double-buffered Bbuf + barrier + af ping-pong.
// R29: exact revert to R25 for all kan layers + tkan_all (row-major ct).
// Single isolated delta: l4_kernel grid 120 -> 240 blocks via blockIdx.z
// slice-split (was 0.47 blocks/CU, half the GPU idle, latency-bound);
// F-build duplicated per z (trivial), part layout + outred unchanged.
// R30: identical resubmit -- R29 bench was an infra failure (container),
// no counters returned; theory unchanged.
// ---------------------------------------------------------------------------

typedef unsigned short u16;
typedef unsigned int   u32;
typedef unsigned long long u64;
typedef __attribute__((ext_vector_type(8))) _Float16 half8;
typedef __attribute__((ext_vector_type(4))) float f32x4;

__device__ __forceinline__ float bf2f(u16 u) {
  u32 v = ((u32)u) << 16;
  return __uint_as_float(v);
}
__device__ __forceinline__ u16 f2bfr(float f) {  // bf16 round-to-nearest-even
  u32 x = __float_as_uint(f);
  u32 r = x + 0x7FFFu + ((x >> 16) & 1u);
  return (u16)(r >> 16);
}
__device__ __forceinline__ u16 f2h(float f) {    // fp16 RTN bits
  _Float16 h = (_Float16)f;
  u16 r;
  __builtin_memcpy(&r, &h, 2);
  return r;
}
__device__ __forceinline__ float h2f(u16 u) {
  _Float16 h;
  __builtin_memcpy(&h, &u, 2);
  return (float)h;
}
// dtype-dispatched external load (flag wave-uniform -> scalar branch)
__device__ __forceinline__ float ldf(const void* p, size_t i, bool f32) {
  return f32 ? ((const float*)p)[i] : bf2f(((const u16*)p)[i]);
}
__device__ __forceinline__ u64 minu64(u64 a, u64 b) { return a < b ? a : b; }

// ---------------- workspace layout (bytes) ----------------
#define NBR_OFF   ((size_t)0)                       // int32 [163840]       655,360
#define FLAG_OFF  ((size_t)917504)                  // int32 [1]
#define L4P_OFF   (((size_t)(1u << 20)) + 131072)   // f32 [8][15][240]     115,200
#define C1T_OFF   (((size_t)(1u << 20)) + 524288)   // fp16 [64][64]          8,192
#define C2T_OFF   (((size_t)(1u << 20)) + 589824)   // fp16 [128][1120]     286,720
#define C3T_OFF   ((size_t)(2u << 20))              // fp16 [1024][2240]  4,587,520
#define C4T_OFF   ((size_t)(7u << 20))              // f32  [40][38400]   6,144,000
#define PMAX_OFF  ((size_t)(13u << 20))             // f32 [256][1024]    1,048,576
#define PSUM_OFF  ((size_t)(14u << 20))             // f32 [256][1024]    1,048,576
#define X1_OFF    ((size_t)(15u << 20))             // fp16 [8192][128]   2,097,152
#define H1_OFF    ((size_t)(18u << 20))             // fp16 [163840][64] 20,971,520
// peak ~39 MB

// ---------------- dtype detector -------------------------------------------
__global__ void detect_kernel(const void* __restrict__ pos,
                              int* __restrict__ flag) {
  int t = threadIdx.x;  // 64 threads
  float a = fabsf(((const float*)pos)[t]);
  bool ok = (a > 1.0e-3f && a < 100.0f);
  unsigned long long m = __ballot(ok);
  if (t == 0) *flag = (__popcll(m) >= 32) ? 1 : 0;  // 1 = fp32 externals
}

// ---------------- merged coeff transpose: all four tensors ------------------
// Angle-major global order: p < 4*NA: aa=p>>2, g=(p&3)+1 ;
// p in [4*NA,5*NA): aa=p-4*NA, g=5. f = 2*p + part. Pad f>=Kt with zeros.
// Block ranges: c1 [0,16) c2 [16,576) c3 [576,9536) c4 [9536,15536).
__global__ void tkan_all_kernel(const void* __restrict__ s1, void* __restrict__ d1,
                                const void* __restrict__ s2, void* __restrict__ d2,
                                const void* __restrict__ s3, void* __restrict__ d3,
                                const void* __restrict__ s4, void* __restrict__ d4,
                                const int* __restrict__ dfl) {
  const int blk = blockIdx.x;
  const void* src; void* dst;
  int dout, nw, W, total, KPAD, outf32, base;
  if (blk < 16)        { src = s1; dst = d1; dout = 64;   nw = 2;  W = 3;
                         total = 64 * 64;     KPAD = 64;    outf32 = 0; base = 0; }
  else if (blk < 576)  { src = s2; dst = d2; dout = 128;  nw = 7;  W = 16;
                         total = 128 * 1120;  KPAD = 1120;  outf32 = 0; base = 16; }
  else if (blk < 9536) { src = s3; dst = d3; dout = 1024; nw = 7;  W = 32;
                         total = 1024 * 2240; KPAD = 2240;  outf32 = 0; base = 576; }
  else                 { src = s4; dst = d4; dout = 40;   nw = 15; W = 256;
                         total = 40 * 38400;  KPAD = 38400; outf32 = 1; base = 9536; }
  int id = (blk - base) * 256 + threadIdx.x;
  if (id >= total) return;
  const bool f32 = (*dfl != 0);
  int o = id / KPAD, f = id % KPAD;
  int NA = nw * W;
  int Kt = NA * 10;
  float v = 0.f;
  if (f < Kt) {
    int part = f & 1, p = f >> 1;
    int aa, gg;
    if (p < 4 * NA) { aa = p >> 2;      gg = p & 3; }
    else            { aa = p - 4 * NA;  gg = 4;     }
    int i = aa % W, w = aa / W;
    int OS = NA * 5;
    size_t sidx = (size_t)part * (dout * OS) + (size_t)o * OS + w * (W * 5) + i * 5 + gg;
    v = ldf(src, sidx, f32);
  }
  if (outf32) ((float*)dst)[id] = v;
  else        ((u16*)dst)[id] = f2h(v);
}

// ---------------- brute-force kNN: one wave per query -----------------------
__global__ __launch_bounds__(256) void knn_kernel(const void* __restrict__ pos,
                                                  int* __restrict__ nbr,
                                                  const int* __restrict__ dfl) {
  __shared__ float px[1024], py[1024], pz[1024];
  const bool f32 = (*dfl != 0);
  const int t = threadIdx.x;
  const int b = blockIdx.y;
  const int base = b << 10;
  for (int j = t; j < 1024; j += 256) {
    size_t pidx = (size_t)(base + j) * 3;
    px[j] = ldf(pos, pidx, f32);
    py[j] = ldf(pos, pidx + 1, f32);
    pz[j] = ldf(pos, pidx + 2, f32);
  }
  __syncthreads();
  const int wv = t >> 6, lane = t & 63;
  const int q = blockIdx.x * 4 + wv;
  const float qx = px[q], qy = py[q], qz = pz[q];
  u64 key[16];
#pragma unroll
  for (int s = 0; s < 16; ++s) {
    const int j = s * 64 + lane;
    float dx = qx - px[j], dy = qy - py[j], dz = qz - pz[j];
    float d = __fadd_rn(__fadd_rn(__fmul_rn(dx, dx), __fmul_rn(dy, dy)),
                        __fmul_rn(dz, dz));
    key[s] = (j == q) ? ~0ull
                      : ((((u64)__float_as_uint(d)) << 32) | (u32)j);
  }
  const int obase = (base + q) * 20;
  for (int k = 0; k < 20; ++k) {
    u64 m = key[0];
#pragma unroll
    for (int s = 1; s < 16; ++s) m = minu64(m, key[s]);
#pragma unroll
    for (int off = 32; off >= 1; off >>= 1) {
      u32 lo = (u32)m, hi = (u32)(m >> 32);
      lo = __shfl_xor(lo, off, 64);
      hi = __shfl_xor(hi, off, 64);
      m = minu64(m, (((u64)hi) << 32) | lo);
    }
    if (lane == 0) nbr[obase + k] = (int)(u32)m;
#pragma unroll
    for (int s = 0; s < 16; ++s)
      if (key[s] == m) key[s] = ~0ull;  // idx embedded -> unique, safe
  }
}

// ---------------- MFMA KAN layer, LDS double-buffered B ---------------------
// Per chunk: 256 threads each load NPC 16B pieces of next chunk's B (4KB or
// 8KB per block, shared by all waves), build NEXT chunk's A fragments
// (slab LDS + trans, pipelined one chunk ahead), MFMA current chunk from
// Bbuf ds_read_b128 (one bv live at a time) + last iter's af, then
// ds_write+barrier. PSTH=DIN+4 halves: lane stride -> 16 distinct banks.
template <int L>
__global__ __launch_bounds__(256, (L == 2) ? 2 : 3) void kan_kernel(
    const void* __restrict__ in_, const int* __restrict__ nbr,
    const void* __restrict__ pos, const u16* __restrict__ ct,
    const void* __restrict__ bias, void* __restrict__ out_,
    float* __restrict__ pmax, float* __restrict__ psum,
    const int* __restrict__ dfl) {
  constexpr int W    = (L == 1) ? 3  : (L == 2) ? 16  : 32;
  constexpr int S    = (L == 1) ? 3  : (L == 2) ? 8   : 16;
  constexpr int DIN  = (L == 1) ? 6  : (L == 2) ? 64  : 128;
  constexpr int NT   = (L == 2) ? 128 : 64;         // L2: full 128-col tile
  constexpr int NW   = (DIN - W) / S + 1;
  constexpr int NA   = NW * W;                      // angles
  constexpr int NPAIR = NA * 5;
  constexpr int S1P  = NA * 4;                      // section-1 pairs (g=1..4)
  constexpr int KROW  = (L == 1) ? 64 : NPAIR * 2;  // ct row stride (padded L1)
  constexpr int NCH   = KROW / 32;                  // L1:2  L2:35(odd!)  L3:70
  constexpr int NB    = NT / 16;                    // 4 or 8
  constexpr int RW    = (L == 1) ? 64 : (L == 2) ? 80 : 32;  // rows per wave
  constexpr int MB    = RW / 16;
  constexpr int PSTH  = DIN + 4;                    // slab stride (halves)
  constexpr int LGW   = (W == 16) ? 4 : 5;          // log2(W) for L2/L3
  constexpr int BCS   = NT * 8 + 8;                 // Bbuf halves per part
  constexpr int BBS   = 4 * BCS;                    // Bbuf halves per buffer
  constexpr int NPC   = NT / 64;                    // 16B B-pieces per thread

  __shared__ float hamS[(L == 1) ? 1 : W];
  __shared__ float wT1[(L == 1) ? 32 : 1];          // L1 tables (padded K=64)
  __shared__ int   hT1[(L == 1) ? 32 : 1];
  __shared__ u16   slab[(L == 1) ? 2 : 4 * RW * PSTH];
  __shared__ u16   stage1[(L == 1) ? 4 * 64 * 64 : 2];
  __shared__ u16   Bbuf[2 * BBS];                   // [buf][part(4)][BCS]

  const bool f32 = (*dfl != 0);
  const u16* inH = (const u16*)in_;
  const int t = threadIdx.x;
  if constexpr (L == 1) {
    if (t < 32) {
      float wv_ = 0.f; int hx = 0;
      if (t < NPAIR) {                              // angle-major mapping
        int aa, gg;
        if (t < S1P) { aa = t >> 2;   gg = t & 3; }
        else         { aa = t - S1P;  gg = 4;     }
        int i = aa % W;
        float hm = 0.54f - 0.46f * cospif(2.0f * (float)i / (float)(W - 1));
        wv_ = hm * (float)(gg + 1);
        hx = aa;                                    // L1 uses aa directly
      }
      wT1[t] = wv_; hT1[t] = hx;
    }
  } else {
    if (t < W) hamS[t] = 0.54f - 0.46f * cospif(2.0f * (float)t / (float)(W - 1));
  }

  // ---- block index: L3 uses XCD-aware swizzle (id%8-equal share 2 slices) --
  int tile, ncol0;
  if constexpr (L == 3) {
    const int id = blockIdx.x;                      // 1024 linear
    tile = (id >> 3) & 63;
    ncol0 = ((((id & 7) << 1) | (id >> 9))) * NT;
  } else {
    tile = blockIdx.x;
    ncol0 = blockIdx.y * NT;
  }
  const int lane = t & 63, wv = t >> 6;
  const int m16 = lane & 15, kb = lane >> 4;
  const int rowbase = tile * (4 * RW) + wv * RW;
  u16* myslab = &slab[(L == 1) ? 0 : wv * RW * PSTH];

  // B staging indices: piece p covers col=p>>2, part=p&3 (16B each)
  const u16* srcB[NPC];
  int sdst[NPC];
#pragma unroll
  for (int p_ = 0; p_ < NPC; ++p_) {
    const int pid = t + p_ * 256;
    const int scol = pid >> 2, spart = pid & 3;
    srcB[p_] = ct + (size_t)(ncol0 + scol) * KROW + spart * 8;
    sdst[p_] = spart * BCS + scol * 8;
  }

  // ---- stage wave-private fp16 slab (L>=2): uint2 = 4 halves ----
  if constexpr (L >= 2) {
    constexpr int F4R = DIN / 4;
    constexpr int TOT = RW * F4R;
    for (int i = lane; i < TOT; i += 64) {
      const int r = i / F4R, c4 = i % F4R;
      *(uint2*)(myslab + r * PSTH + c4 * 4) =
          *(const uint2*)(inH + (size_t)(rowbase + r) * DIN + c4 * 4);
    }
  }

  // ---- prologue: stage B chunk 0 ----
#pragma unroll
  for (int p_ = 0; p_ < NPC; ++p_) {
    const uint4 v = *(const uint4*)srcB[p_];
    *(uint4*)(Bbuf + sdst[p_]) = v;
  }
  __syncthreads();  // covers hamS/tables + Bbuf[0]

  f32x4 acc[MB][NB];
#pragma unroll
  for (int mb = 0; mb < MB; ++mb)
#pragma unroll
    for (int nb = 0; nb < NB; ++nb) {
      acc[mb][nb][0] = 0.f; acc[mb][nb][1] = 0.f;
      acc[mb][nb][2] = 0.f; acc[mb][nb][3] = 0.f;
    }

  // ---- A-fragment builder for chunk c (reads slab / pos only) ----
  auto build_af = [&](int c, half8* af) {
    const int pg0 = c * 16 + kb * 4;
    if constexpr (L == 1) {
      float wm[4]; int hx[4]; bool val[4];
#pragma unroll
      for (int u = 0; u < 4; ++u) {
        const int pg = pg0 + u;
        wm[u] = wT1[pg]; hx[u] = hT1[pg]; val[u] = (pg < NPAIR);
      }
#pragma unroll
      for (int mb = 0; mb < MB; ++mb) {
        const int row = rowbase + mb * 16 + m16;
        const int pt = row / 20;
        const int cloud = pt >> 10, ci = pt & 1023;
        const int cb = cloud << 10;
        const int jl = nbr[row];
#pragma unroll
        for (int u = 0; u < 4; ++u) {
          float cs = 0.f, sn = 0.f;
          if (val[u]) {
            const int aa = hx[u];
            float v;
            if (aa < 3) {
              v = ldf(pos, (size_t)(cb + ci) * 3 + aa, f32);
            } else {
              const int cc2 = aa - 3;
              v = ldf(pos, (size_t)(cb + jl) * 3 + cc2, f32) -
                  ldf(pos, (size_t)(cb + ci) * 3 + cc2, f32);
            }
            const float ang = v * wm[u];
            cs = __cosf(ang); sn = __sinf(ang);
          }
          af[mb][2 * u]     = (_Float16)cs;
          af[mb][2 * u + 1] = (_Float16)sn;
        }
      }
    } else if (pg0 < S1P) {
      // section 1: one angle, g=1..4 -> Chebyshev recurrence
      const int aa = pg0 >> 2;
      const int i = aa & (W - 1), w = aa >> LGW;
      const int hidx = S * w + i;
      const float hm = hamS[i];
#pragma unroll
      for (int mb = 0; mb < MB; ++mb) {
        const u16* rp = myslab + (mb * 16 + m16) * PSTH;
        const float th = h2f(rp[hidx]) * hm;
        const float c1 = __cosf(th), s1 = __sinf(th);
        const float tc = 2.0f * c1;
        const float c2 = tc * c1 - 1.0f, s2 = tc * s1;
        const float c3 = tc * c2 - c1,   s3 = tc * s2 - s1;
        const float c4 = tc * c3 - c2,   s4 = tc * s3 - s2;
        af[mb][0] = (_Float16)c1; af[mb][1] = (_Float16)s1;
        af[mb][2] = (_Float16)c2; af[mb][3] = (_Float16)s2;
        af[mb][4] = (_Float16)c3; af[mb][5] = (_Float16)s3;
        af[mb][6] = (_Float16)c4; af[mb][7] = (_Float16)s4;
      }
    } else {
      // section 2: g=5 tail, 4 distinct angles, direct cos/sin
      const int q0 = pg0 - S1P;
      float wm[4]; int hx[4];
#pragma unroll
      for (int u = 0; u < 4; ++u) {
        const int aa = q0 + u;
        const int i = aa & (W - 1), w = aa >> LGW;
        hx[u] = S * w + i;
        wm[u] = hamS[i] * 5.0f;
      }
#pragma unroll
      for (int mb = 0; mb < MB; ++mb) {
        const u16* rp = myslab + (mb * 16 + m16) * PSTH;
#pragma unroll
        for (int u = 0; u < 4; ++u) {
          const float ang = h2f(rp[hx[u]]) * wm[u];
          af[mb][2 * u]     = (_Float16)__cosf(ang);
          af[mb][2 * u + 1] = (_Float16)__sinf(ang);
        }
      }
    }
  };

  // ---- one pipelined chunk: uses afc (built last iter), builds afn ----
  auto step = [&](int c, half8* afc, half8* afn) {
    const bool havenext = (c + 1 < NCH);
    // issue next chunk's B global load (overlaps everything below)
    uint4 bnext[NPC];
    if (havenext) {
#pragma unroll
      for (int p_ = 0; p_ < NPC; ++p_)
        bnext[p_] = *(const uint4*)(srcB[p_] + (c + 1) * 32);
    }
    // build NEXT chunk's A fragments; MFMA below consumes afc from LAST
    // iter -> trans chain off the MFMA critical path
    if (havenext) build_af(c + 1, afn);
    // MFMA: bv loaded per-nb (R24 hoisted all NB upfront -> +32 VGPR live
    // across build_af -> scratch spill, WRITE 37.7MB. Keep live set small.)
    const u16* bb = Bbuf + (c & 1) * BBS + kb * BCS;
#pragma unroll
    for (int nb = 0; nb < NB; ++nb) {
      const half8 bv = *(const half8*)(bb + (nb * 16 + m16) * 8);
#pragma unroll
      for (int mb = 0; mb < MB; ++mb)
        acc[mb][nb] = __builtin_amdgcn_mfma_f32_16x16x32_f16(
            afc[mb], bv, acc[mb][nb], 0, 0, 0);
    }
    // commit next chunk's B to LDS, barrier
    if (havenext) {
#pragma unroll
      for (int p_ = 0; p_ < NPC; ++p_)
        *(uint4*)(Bbuf + ((c + 1) & 1) * BBS + sdst[p_]) = bnext[p_];
      __syncthreads();
    }
  };

  half8 afA[MB], afB[MB];
  build_af(0, afA);
  constexpr int NCH2 = (NCH / 2) * 2;  // even part: L1 2, L2 34, L3 70
  for (int c = 0; c < NCH2; c += 2) {
    step(c, afA, afB);
    step(c + 1, afB, afA);
  }
  if constexpr ((NCH & 1) != 0) {
    // odd tail (L2: c=34). step(NCH2-1, afB, afA) built afA=af(NCH-1);
    // buf[(NCH-1)&1] was committed+barriered there. Consume it.
    step(NCH - 1, afA, afB);
  }

  // ---- fused epilogues (C layout: row=kb*4+r, col=m16 within 16x16) ----
  if constexpr (L == 1) {
    // stage wave C-tile (64 rows x 64 cols fp16) then contiguous copy out
    u16* st = &stage1[wv * 4096];
#pragma unroll
    for (int mb = 0; mb < MB; ++mb)
#pragma unroll
      for (int nb = 0; nb < NB; ++nb) {
        const float bsv = ldf(bias, nb * 16 + m16, f32);
#pragma unroll
        for (int r = 0; r < 4; ++r)
          st[(mb * 16 + kb * 4 + r) * 64 + nb * 16 + m16] =
              f2h(acc[mb][nb][r] + bsv);
      }
    u16* gp = (u16*)out_ + (size_t)rowbase * 64;
    for (int i = lane; i < 512; i += 64)        // 512 x 16B = 8KB
      *(uint4*)(gp + i * 8) = *(const uint4*)&st[i * 8];
  } else if constexpr (L == 2) {
    // C-tile (80x128) -> dead slab (stride PSTH) in two 64-col passes,
    // maxpool over 20 rows each pass, write x1 fp16
    u16* st = myslab;
    const int pbase = tile * 16 + wv * 4;       // 4 points per wave
#pragma unroll
    for (int h = 0; h < 2; ++h) {
#pragma unroll
      for (int mb = 0; mb < MB; ++mb)
#pragma unroll
        for (int nb4 = 0; nb4 < 4; ++nb4) {
          const int nb = h * 4 + nb4;
          const float bsv = ldf(bias, ncol0 + nb * 16 + m16, f32);
#pragma unroll
          for (int r = 0; r < 4; ++r)
            st[(mb * 16 + kb * 4 + r) * PSTH + nb4 * 16 + m16] =
                f2h(acc[mb][nb][r] + bsv);
        }
#pragma unroll
      for (int j = 0; j < 4; ++j) {
        float m = -3.0e38f;
#pragma unroll
        for (int k = 0; k < 20; ++k)
          m = fmaxf(m, h2f(st[(j * 20 + k) * PSTH + lane]));
        ((u16*)out_)[(size_t)(pbase + j) * 128 + ncol0 + h * 64 + lane] = f2h(m);
      }
    }
  } else {
    // in-register max/sum over 32 rows + kb butterfly -> pmax/psum partials
    const int chunk = rowbase >> 5;
#pragma unroll
    for (int nb = 0; nb < NB; ++nb) {
      const int col = ncol0 + nb * 16 + m16;
      const float bsv = ldf(bias, col, f32);
      float m = -3.0e38f, s = 0.f;
#pragma unroll
      for (int mb = 0; mb < MB; ++mb)
#pragma unroll
        for (int r = 0; r < 4; ++r) {
          const float v = acc[mb][nb][r] + bsv;
          m = fmaxf(m, v); s += v;
        }
#pragma unroll
      for (int off = 16; off <= 32; off <<= 1) {
        m = fmaxf(m, __shfl_xor(m, off, 64));
        s += __shfl_xor(s, off, 64);
      }
      if (kb == 0) {
        pmax[(size_t)chunk * 1024 + col] = m;
        psum[(size_t)chunk * 1024 + col] = s;
      }
    }
  }
}

// ---------------- layer 4 partials (seg reduce fused in) --------------------
// c4t GLOBAL layout (angle-major): window w section-1 (g1..4 quads) at
// o*38400 + w*2048 ; g5 tail at o*38400 + 30720 + w*512.
// R29: grid (15,8,2) -- z splits the 6 dot slices into 2x3 (240 blocks,
// was 120 = 0.47/CU). F build duplicated per z (cheap); part layout same.
__global__ __launch_bounds__(256) void l4_kernel(const float* __restrict__ pmax,
                                                 const float* __restrict__ psum,
                                                 const float* __restrict__ c4t,
                                                 float* __restrict__ part) {
  __shared__ float F[2560];
  const int t = threadIdx.x;
  const int w = blockIdx.x, b = blockIdx.y, z = blockIdx.z;
  // fused segment combine (same reduce order as former seg2)
  const int ch = w * 128 + t;
  float xv;
  if (ch < 1024) {
    float m = -3.0e38f;
    for (int rc = 0; rc < 32; ++rc)
      m = fmaxf(m, pmax[(size_t)(b * 32 + rc) * 1024 + ch]);
    xv = m;
  } else {
    const int cc = ch - 1024;
    float s = 0.f;
    for (int rc = 0; rc < 32; ++rc)
      s += psum[(size_t)(b * 32 + rc) * 1024 + cc];
    xv = s * (1.0f / 1024.0f);
  }
  const float hm = 0.54f - 0.46f * cospif(2.0f * (float)t / 255.0f);
  const float aa = xv * hm;
  const float c1 = __cosf(aa), s1 = __sinf(aa);
  const float tc = 2.0f * c1;
  const float c2 = tc * c1 - 1.0f, s2 = tc * s1;
  const float c3 = tc * c2 - c1,   s3 = tc * s2 - s1;
  const float c4 = tc * c3 - c2,   s4 = tc * s3 - s2;
  const float a5 = aa * 5.0f;
  F[t * 8]     = c1; F[t * 8 + 1] = s1;
  F[t * 8 + 2] = c2; F[t * 8 + 3] = s2;
  F[t * 8 + 4] = c3; F[t * 8 + 5] = s3;
  F[t * 8 + 6] = c4; F[t * 8 + 7] = s4;
  F[2048 + t * 2]     = __cosf(a5);
  F[2048 + t * 2 + 1] = __sinf(a5);
  __syncthreads();
  if (t < 120) {
    const int o = t % 40, sl = t / 40;          // sl in [0,3)
    const int s = z * 3 + sl;                   // s in [0,6)
    const int f0 = s * 432;
    const int f1 = (f0 + 432 < 2560) ? (f0 + 432) : 2560;
    const float* cp1 = c4t + (size_t)o * 38400 + w * 2048;          // sec 1
    const float* cp2 = c4t + (size_t)o * 38400 + 30720 + w * 512;   // g5 tail
    float acc = 0.f;
    for (int f = f0; f < f1; f += 4) {   // 2048 boundary is float4-aligned
      const float* cpf = (f < 2048) ? (cp1 + f) : (cp2 + (f - 2048));
      const float4 cv = *(const float4*)cpf;
      const float4 fa = *(const float4*)&F[f];
      acc += fa.x * cv.x + fa.y * cv.y + fa.z * cv.z + fa.w * cv.w;
    }
    part[((b * 15 + w) * 6 + s) * 40 + o] = acc;
  }
}

__global__ void outred_kernel(const float* __restrict__ part,
                              const void* __restrict__ b4,
                              void* __restrict__ outp,
                              const int* __restrict__ dfl) {
  int t = threadIdx.x;
  if (t >= 320) return;
  const bool f32 = (*dfl != 0);
  int b = t / 40, o = t % 40;
  float s = ldf(b4, o, f32);
  for (int w = 0; w < 15; ++w)
#pragma unroll
    for (int sl = 0; sl < 6; ++sl)
      s += part[((b * 15 + w) * 6 + sl) * 40 + o];
  if (f32) ((float*)outp)[t] = s;
  else     ((u16*)outp)[t] = f2bfr(s);
}

// ---------------------------------------------------------------------------
extern "C" void kernel_launch(void* const* d_in, const int* in_sizes, int n_in,
                              void* d_out, int out_size, void* d_ws,
                              size_t ws_size, hipStream_t stream) {
  (void)in_sizes; (void)n_in; (void)out_size; (void)ws_size;
  const void* pos = d_in[0];
  // d_in[1] = batch (int32) -- clouds are sorted equal-size, used implicitly
  const void* c1 = d_in[2];
  const void* b1 = d_in[3];
  const void* c2 = d_in[4];
  const void* b2 = d_in[5];
  const void* c3 = d_in[6];
  const void* b3 = d_in[7];
  const void* c4 = d_in[8];
  const void* b4 = d_in[9];

  char* ws = (char*)d_ws;
  int* nbr   = (int*)(ws + NBR_OFF);
  int* flag  = (int*)(ws + FLAG_OFF);
  float* l4p = (float*)(ws + L4P_OFF);
  u16* c1t   = (u16*)(ws + C1T_OFF);
  u16* c2t   = (u16*)(ws + C2T_OFF);
  u16* c3t   = (u16*)(ws + C3T_OFF);
  float* c4t = (float*)(ws + C4T_OFF);
  float* pmax = (float*)(ws + PMAX_OFF);
  float* psum = (float*)(ws + PSUM_OFF);
  u16* x1    = (u16*)(ws + X1_OFF);
  u16* h1    = (u16*)(ws + H1_OFF);

  detect_kernel<<<1, 64, 0, stream>>>(pos, flag);

  tkan_all_kernel<<<15536, 256, 0, stream>>>(c1, c1t, c2, c2t, c3, c3t,
                                             c4, c4t, flag);

  knn_kernel<<<dim3(256, 8), 256, 0, stream>>>(pos, nbr, flag);

  // L1: 640 blocks x 256 rows, NT=DOUT=64
  kan_kernel<1><<<640, 256, 0, stream>>>(nullptr, nbr, pos, c1t, b1, h1,
                                         nullptr, nullptr, flag);
  // L2 fused maxpool: 512 blocks x 320 rows (16 points), NT=128 single-pass
  // over columns (A-compute shared), 2 blocks/CU, af pipelined 1 chunk ahead
  kan_kernel<2><<<dim3(512), 256, 0, stream>>>(h1, nullptr, nullptr, c2t,
                                               b2, x1, nullptr, nullptr, flag);
  // L3 fused segment partials: 1024 linear blocks, XCD-swizzled inside
  kan_kernel<3><<<1024, 256, 0, stream>>>(x1, nullptr, nullptr, c3t,
                                          b3, nullptr, pmax, psum, flag);

  l4_kernel<<<dim3(15, 8, 2), 256, 0, stream>>>(pmax, psum, c4t, l4p);
  outred_kernel<<<1, 320, 0, stream>>>(l4p, b4, d_out, flag);
}

// Round 11
// 284.938 us; speedup vs baseline: 1.4441x; 1.0300x over previous
//
#include <hip/hip_runtime.h>

// ---------------------------------------------------------------------------
// STFT-Fourier-KAN DGCNN on MI355X.
// R30 (293.5us, best): R25 kan layers + l4 z-split (240 blocks). kan<2>~74,
// kan<3>~75 -- plateau structural (5 levers each neutral/negative: VALU-halve,
// af-pipeline, barrier-free, NB=16 ratio, RW/occupancy). Tail ~144us but
// bottom-up kernel arithmetic only accounts ~65 -> residual ~= launch/drain
// overhead of 8 sequential stream kernels (~10us/boundary per rocprof.md).
// R31: kernel count 8->6, co-schedule independent work. (1) detect_kernel
// deleted -- flag recomputed per-wave via ballot(pos[lane&63]) in every
// consumer (identical decision, no global roundtrip). (2) knn + tkan_all
// merged into prep_kernel (knn blocks [0,2048) first, tkan [2048,17584));
// independent work co-executes: knn VALU/LDS fills tkan's HBM-gather
// latency. (3) tkan templated on tensor -> literal KPAD/W: magic-mul
// division. kan K-loops byte-identical to R30.
// ---------------------------------------------------------------------------

typedef unsigned short u16;
typedef unsigned int   u32;
typedef unsigned long long u64;
typedef __attribute__((ext_vector_type(8))) _Float16 half8;
typedef __attribute__((ext_vector_type(4))) float f32x4;

__device__ __forceinline__ float bf2f(u16 u) {
  u32 v = ((u32)u) << 16;
  return __uint_as_float(v);
}
__device__ __forceinline__ u16 f2bfr(float f) {  // bf16 round-to-nearest-even
  u32 x = __float_as_uint(f);
  u32 r = x + 0x7FFFu + ((x >> 16) & 1u);
  return (u16)(r >> 16);
}
__device__ __forceinline__ u16 f2h(float f) {    // fp16 RTN bits
  _Float16 h = (_Float16)f;
  u16 r;
  __builtin_memcpy(&r, &h, 2);
  return r;
}
__device__ __forceinline__ float h2f(u16 u) {
  _Float16 h;
  __builtin_memcpy(&h, &u, 2);
  return (float)h;
}
// dtype-dispatched external load (flag wave-uniform -> scalar branch)
__device__ __forceinline__ float ldf(const void* p, size_t i, bool f32) {
  return f32 ? ((const float*)p)[i] : bf2f(((const u16*)p)[i]);
}
__device__ __forceinline__ u64 minu64(u64 a, u64 b) { return a < b ? a : b; }

// per-wave dtype detect: every wave reads pos[0..63] as f32 and ballots the
// "plausible float" test -- identical decision to the old detect_kernel,
// wave-uniform result, no global flag roundtrip.
__device__ __forceinline__ bool wave_detect(const void* pos) {
  float a = fabsf(((const float*)pos)[threadIdx.x & 63]);
  bool ok = (a > 1.0e-3f && a < 100.0f);
  unsigned long long m = __ballot(ok);
  return __popcll(m) >= 32;
}

// ---------------- workspace layout (bytes) ----------------
#define NBR_OFF   ((size_t)0)                       // int32 [163840]       655,360
#define L4P_OFF   (((size_t)(1u << 20)) + 131072)   // f32 [8][15][240]     115,200
#define C1T_OFF   (((size_t)(1u << 20)) + 524288)   // fp16 [64][64]          8,192
#define C2T_OFF   (((size_t)(1u << 20)) + 589824)   // fp16 [128][1120]     286,720
#define C3T_OFF   ((size_t)(2u << 20))              // fp16 [1024][2240]  4,587,520
#define C4T_OFF   ((size_t)(7u << 20))              // f32  [40][38400]   6,144,000
#define PMAX_OFF  ((size_t)(13u << 20))             // f32 [256][1024]    1,048,576
#define PSUM_OFF  ((size_t)(14u << 20))             // f32 [256][1024]    1,048,576
#define X1_OFF    ((size_t)(15u << 20))             // fp16 [8192][128]   2,097,152
#define H1_OFF    ((size_t)(18u << 20))             // fp16 [163840][64] 20,971,520
// peak ~39 MB

// ---------------- tkan transpose body (compile-time constants) --------------
// Angle-major k-order: p < 4*NA: aa=p>>2, g=(p&3)+1 ; p in [4*NA,5*NA):
// aa=p-4*NA, g=5. f = 2*p + part. Pad f>=Kt with zeros.
template <int DOUT, int NW, int WW, int KPAD, int OUTF32>
__device__ __forceinline__ void tkan_body(const void* __restrict__ src,
                                          void* __restrict__ dst,
                                          int id, bool f32) {
  constexpr int NA = NW * WW;
  constexpr int Kt = NA * 10;
  constexpr int OS = NA * 5;
  const int o = id / KPAD, f = id % KPAD;   // literal KPAD -> magic multiply
  float v = 0.f;
  if (f < Kt) {
    const int part = f & 1, p = f >> 1;
    int aa, gg;
    if (p < 4 * NA) { aa = p >> 2;      gg = p & 3; }
    else            { aa = p - 4 * NA;  gg = 4;     }
    const int i = aa % WW, w = aa / WW;     // literal WW
    size_t sidx = (size_t)part * (DOUT * OS) + (size_t)o * OS +
                  (size_t)w * (WW * 5) + i * 5 + gg;
    v = ldf(src, sidx, f32);
  }
  if (OUTF32) ((float*)dst)[id] = v;
  else        ((u16*)dst)[id] = f2h(v);
}

// ---------------- merged prep: knn [0,2048) + coeff transpose [2048,17584) --
// knn and tkan are mutually independent (pos vs coeffs) -> one launch,
// co-scheduled: knn's VALU/shuffle work overlaps tkan's scattered HBM reads.
__global__ __launch_bounds__(256) void prep_kernel(
    const void* __restrict__ pos, int* __restrict__ nbr,
    const void* __restrict__ s1, void* __restrict__ d1,
    const void* __restrict__ s2, void* __restrict__ d2,
    const void* __restrict__ s3, void* __restrict__ d3,
    const void* __restrict__ s4, void* __restrict__ d4) {
  __shared__ float px[1024], py[1024], pz[1024];
  const bool f32 = wave_detect(pos);
  const int blk = blockIdx.x;
  const int t = threadIdx.x;

  if (blk >= 2048) {                         // ---- coeff transpose part ----
    const int tb = blk - 2048;
    if (tb < 16) {
      tkan_body<64, 2, 3, 64, 0>(s1, d1, tb * 256 + t, f32);
    } else if (tb < 576) {
      tkan_body<128, 7, 16, 1120, 0>(s2, d2, (tb - 16) * 256 + t, f32);
    } else if (tb < 9536) {
      tkan_body<1024, 7, 32, 2240, 0>(s3, d3, (tb - 576) * 256 + t, f32);
    } else {
      tkan_body<40, 15, 256, 38400, 1>(s4, d4, (tb - 9536) * 256 + t, f32);
    }
    return;
  }

  // ---- brute-force kNN: one wave per query ----
  const int b = blk >> 8;                    // cloud [0,8)
  const int x = blk & 255;                   // query group [0,256)
  const int base = b << 10;
  for (int j = t; j < 1024; j += 256) {
    size_t pidx = (size_t)(base + j) * 3;
    px[j] = ldf(pos, pidx, f32);
    py[j] = ldf(pos, pidx + 1, f32);
    pz[j] = ldf(pos, pidx + 2, f32);
  }
  __syncthreads();
  const int wv = t >> 6, lane = t & 63;
  const int q = x * 4 + wv;
  const float qx = px[q], qy = py[q], qz = pz[q];
  u64 key[16];
#pragma unroll
  for (int s = 0; s < 16; ++s) {
    const int j = s * 64 + lane;
    float dx = qx - px[j], dy = qy - py[j], dz = qz - pz[j];
    float d = __fadd_rn(__fadd_rn(__fmul_rn(dx, dx), __fmul_rn(dy, dy)),
                        __fmul_rn(dz, dz));
    key[s] = (j == q) ? ~0ull
                      : ((((u64)__float_as_uint(d)) << 32) | (u32)j);
  }
  const int obase = (base + q) * 20;
  for (int k = 0; k < 20; ++k) {
    u64 m = key[0];
#pragma unroll
    for (int s = 1; s < 16; ++s) m = minu64(m, key[s]);
#pragma unroll
    for (int off = 32; off >= 1; off >>= 1) {
      u32 lo = (u32)m, hi = (u32)(m >> 32);
      lo = __shfl_xor(lo, off, 64);
      hi = __shfl_xor(hi, off, 64);
      m = minu64(m, (((u64)hi) << 32) | lo);
    }
    if (lane == 0) nbr[obase + k] = (int)(u32)m;
#pragma unroll
    for (int s = 0; s < 16; ++s)
      if (key[s] == m) key[s] = ~0ull;  // idx embedded -> unique, safe
  }
}

// ---------------- MFMA KAN layer, LDS double-buffered B ---------------------
// Per chunk: 256 threads each load NPC 16B pieces of next chunk's B (4KB or
// 8KB per block, shared by all waves), build NEXT chunk's A fragments
// (slab LDS + trans, pipelined one chunk ahead), MFMA current chunk from
// Bbuf ds_read_b128 (one bv live at a time) + last iter's af, then
// ds_write+barrier. PSTH=DIN+4 halves: lane stride -> 16 distinct banks.
template <int L>
__global__ __launch_bounds__(256, (L == 2) ? 2 : 3) void kan_kernel(
    const void* __restrict__ in_, const int* __restrict__ nbr,
    const void* __restrict__ pos, const u16* __restrict__ ct,
    const void* __restrict__ bias, void* __restrict__ out_,
    float* __restrict__ pmax, float* __restrict__ psum) {
  constexpr int W    = (L == 1) ? 3  : (L == 2) ? 16  : 32;
  constexpr int S    = (L == 1) ? 3  : (L == 2) ? 8   : 16;
  constexpr int DIN  = (L == 1) ? 6  : (L == 2) ? 64  : 128;
  constexpr int NT   = (L == 2) ? 128 : 64;         // L2: full 128-col tile
  constexpr int NW   = (DIN - W) / S + 1;
  constexpr int NA   = NW * W;                      // angles
  constexpr int NPAIR = NA * 5;
  constexpr int S1P  = NA * 4;                      // section-1 pairs (g=1..4)
  constexpr int KROW  = (L == 1) ? 64 : NPAIR * 2;  // ct row stride (padded L1)
  constexpr int NCH   = KROW / 32;                  // L1:2  L2:35(odd!)  L3:70
  constexpr int NB    = NT / 16;                    // 4 or 8
  constexpr int RW    = (L == 1) ? 64 : (L == 2) ? 80 : 32;  // rows per wave
  constexpr int MB    = RW / 16;
  constexpr int PSTH  = DIN + 4;                    // slab stride (halves)
  constexpr int LGW   = (W == 16) ? 4 : 5;          // log2(W) for L2/L3
  constexpr int BCS   = NT * 8 + 8;                 // Bbuf halves per part
  constexpr int BBS   = 4 * BCS;                    // Bbuf halves per buffer
  constexpr int NPC   = NT / 64;                    // 16B B-pieces per thread

  __shared__ float hamS[(L == 1) ? 1 : W];
  __shared__ float wT1[(L == 1) ? 32 : 1];          // L1 tables (padded K=64)
  __shared__ int   hT1[(L == 1) ? 32 : 1];
  __shared__ u16   slab[(L == 1) ? 2 : 4 * RW * PSTH];
  __shared__ u16   stage1[(L == 1) ? 4 * 64 * 64 : 2];
  __shared__ u16   Bbuf[2 * BBS];                   // [buf][part(4)][BCS]

  const bool f32 = wave_detect(pos);
  const u16* inH = (const u16*)in_;
  const int t = threadIdx.x;
  if constexpr (L == 1) {
    if (t < 32) {
      float wv_ = 0.f; int hx = 0;
      if (t < NPAIR) {                              // angle-major mapping
        int aa, gg;
        if (t < S1P) { aa = t >> 2;   gg = t & 3; }
        else         { aa = t - S1P;  gg = 4;     }
        int i = aa % W;
        float hm = 0.54f - 0.46f * cospif(2.0f * (float)i / (float)(W - 1));
        wv_ = hm * (float)(gg + 1);
        hx = aa;                                    // L1 uses aa directly
      }
      wT1[t] = wv_; hT1[t] = hx;
    }
  } else {
    if (t < W) hamS[t] = 0.54f - 0.46f * cospif(2.0f * (float)t / (float)(W - 1));
  }

  // ---- block index: L3 uses XCD-aware swizzle (id%8-equal share 2 slices) --
  int tile, ncol0;
  if constexpr (L == 3) {
    const int id = blockIdx.x;                      // 1024 linear
    tile = (id >> 3) & 63;
    ncol0 = ((((id & 7) << 1) | (id >> 9))) * NT;
  } else {
    tile = blockIdx.x;
    ncol0 = blockIdx.y * NT;
  }
  const int lane = t & 63, wv = t >> 6;
  const int m16 = lane & 15, kb = lane >> 4;
  const int rowbase = tile * (4 * RW) + wv * RW;
  u16* myslab = &slab[(L == 1) ? 0 : wv * RW * PSTH];

  // B staging indices: piece p covers col=p>>2, part=p&3 (16B each)
  const u16* srcB[NPC];
  int sdst[NPC];
#pragma unroll
  for (int p_ = 0; p_ < NPC; ++p_) {
    const int pid = t + p_ * 256;
    const int scol = pid >> 2, spart = pid & 3;
    srcB[p_] = ct + (size_t)(ncol0 + scol) * KROW + spart * 8;
    sdst[p_] = spart * BCS + scol * 8;
  }

  // ---- stage wave-private fp16 slab (L>=2): uint2 = 4 halves ----
  if constexpr (L >= 2) {
    constexpr int F4R = DIN / 4;
    constexpr int TOT = RW * F4R;
    for (int i = lane; i < TOT; i += 64) {
      const int r = i / F4R, c4 = i % F4R;
      *(uint2*)(myslab + r * PSTH + c4 * 4) =
          *(const uint2*)(inH + (size_t)(rowbase + r) * DIN + c4 * 4);
    }
  }

  // ---- prologue: stage B chunk 0 ----
#pragma unroll
  for (int p_ = 0; p_ < NPC; ++p_) {
    const uint4 v = *(const uint4*)srcB[p_];
    *(uint4*)(Bbuf + sdst[p_]) = v;
  }
  __syncthreads();  // covers hamS/tables + Bbuf[0]

  f32x4 acc[MB][NB];
#pragma unroll
  for (int mb = 0; mb < MB; ++mb)
#pragma unroll
    for (int nb = 0; nb < NB; ++nb) {
      acc[mb][nb][0] = 0.f; acc[mb][nb][1] = 0.f;
      acc[mb][nb][2] = 0.f; acc[mb][nb][3] = 0.f;
    }

  // ---- A-fragment builder for chunk c (reads slab / pos only) ----
  auto build_af = [&](int c, half8* af) {
    const int pg0 = c * 16 + kb * 4;
    if constexpr (L == 1) {
      float wm[4]; int hx[4]; bool val[4];
#pragma unroll
      for (int u = 0; u < 4; ++u) {
        const int pg = pg0 + u;
        wm[u] = wT1[pg]; hx[u] = hT1[pg]; val[u] = (pg < NPAIR);
      }
#pragma unroll
      for (int mb = 0; mb < MB; ++mb) {
        const int row = rowbase + mb * 16 + m16;
        const int pt = row / 20;
        const int cloud = pt >> 10, ci = pt & 1023;
        const int cb = cloud << 10;
        const int jl = nbr[row];
#pragma unroll
        for (int u = 0; u < 4; ++u) {
          float cs = 0.f, sn = 0.f;
          if (val[u]) {
            const int aa = hx[u];
            float v;
            if (aa < 3) {
              v = ldf(pos, (size_t)(cb + ci) * 3 + aa, f32);
            } else {
              const int cc2 = aa - 3;
              v = ldf(pos, (size_t)(cb + jl) * 3 + cc2, f32) -
                  ldf(pos, (size_t)(cb + ci) * 3 + cc2, f32);
            }
            const float ang = v * wm[u];
            cs = __cosf(ang); sn = __sinf(ang);
          }
          af[mb][2 * u]     = (_Float16)cs;
          af[mb][2 * u + 1] = (_Float16)sn;
        }
      }
    } else if (pg0 < S1P) {
      // section 1: one angle, g=1..4 -> Chebyshev recurrence
      const int aa = pg0 >> 2;
      const int i = aa & (W - 1), w = aa >> LGW;
      const int hidx = S * w + i;
      const float hm = hamS[i];
#pragma unroll
      for (int mb = 0; mb < MB; ++mb) {
        const u16* rp = myslab + (mb * 16 + m16) * PSTH;
        const float th = h2f(rp[hidx]) * hm;
        const float c1 = __cosf(th), s1 = __sinf(th);
        const float tc = 2.0f * c1;
        const float c2 = tc * c1 - 1.0f, s2 = tc * s1;
        const float c3 = tc * c2 - c1,   s3 = tc * s2 - s1;
        const float c4 = tc * c3 - c2,   s4 = tc * s3 - s2;
        af[mb][0] = (_Float16)c1; af[mb][1] = (_Float16)s1;
        af[mb][2] = (_Float16)c2; af[mb][3] = (_Float16)s2;
        af[mb][4] = (_Float16)c3; af[mb][5] = (_Float16)s3;
        af[mb][6] = (_Float16)c4; af[mb][7] = (_Float16)s4;
      }
    } else {
      // section 2: g=5 tail, 4 distinct angles, direct cos/sin
      const int q0 = pg0 - S1P;
      float wm[4]; int hx[4];
#pragma unroll
      for (int u = 0; u < 4; ++u) {
        const int aa = q0 + u;
        const int i = aa & (W - 1), w = aa >> LGW;
        hx[u] = S * w + i;
        wm[u] = hamS[i] * 5.0f;
      }
#pragma unroll
      for (int mb = 0; mb < MB; ++mb) {
        const u16* rp = myslab + (mb * 16 + m16) * PSTH;
#pragma unroll
        for (int u = 0; u < 4; ++u) {
          const float ang = h2f(rp[hx[u]]) * wm[u];
          af[mb][2 * u]     = (_Float16)__cosf(ang);
          af[mb][2 * u + 1] = (_Float16)__sinf(ang);
        }
      }
    }
  };

  // ---- one pipelined chunk: uses afc (built last iter), builds afn ----
  auto step = [&](int c, half8* afc, half8* afn) {
    const bool havenext = (c + 1 < NCH);
    // issue next chunk's B global load (overlaps everything below)
    uint4 bnext[NPC];
    if (havenext) {
#pragma unroll
      for (int p_ = 0; p_ < NPC; ++p_)
        bnext[p_] = *(const uint4*)(srcB[p_] + (c + 1) * 32);
    }
    // build NEXT chunk's A fragments; MFMA below consumes afc from LAST
    // iter -> trans chain off the MFMA critical path
    if (havenext) build_af(c + 1, afn);
    // MFMA: bv loaded per-nb (R24 hoisted all NB upfront -> +32 VGPR live
    // across build_af -> scratch spill. Keep live set small.)
    const u16* bb = Bbuf + (c & 1) * BBS + kb * BCS;
#pragma unroll
    for (int nb = 0; nb < NB; ++nb) {
      const half8 bv = *(const half8*)(bb + (nb * 16 + m16) * 8);
#pragma unroll
      for (int mb = 0; mb < MB; ++mb)
        acc[mb][nb] = __builtin_amdgcn_mfma_f32_16x16x32_f16(
            afc[mb], bv, acc[mb][nb], 0, 0, 0);
    }
    // commit next chunk's B to LDS, barrier
    if (havenext) {
#pragma unroll
      for (int p_ = 0; p_ < NPC; ++p_)
        *(uint4*)(Bbuf + ((c + 1) & 1) * BBS + sdst[p_]) = bnext[p_];
      __syncthreads();
    }
  };

  half8 afA[MB], afB[MB];
  build_af(0, afA);
  constexpr int NCH2 = (NCH / 2) * 2;  // even part: L1 2, L2 34, L3 70
  for (int c = 0; c < NCH2; c += 2) {
    step(c, afA, afB);
    step(c + 1, afB, afA);
  }
  if constexpr ((NCH & 1) != 0) {
    // odd tail (L2: c=34). step(NCH2-1, afB, afA) built afA=af(NCH-1);
    // buf[(NCH-1)&1] was committed+barriered there. Consume it.
    step(NCH - 1, afA, afB);
  }

  // ---- fused epilogues (C layout: row=kb*4+r, col=m16 within 16x16) ----
  if constexpr (L == 1) {
    // stage wave C-tile (64 rows x 64 cols fp16) then contiguous copy out
    u16* st = &stage1[wv * 4096];
#pragma unroll
    for (int mb = 0; mb < MB; ++mb)
#pragma unroll
      for (int nb = 0; nb < NB; ++nb) {
        const float bsv = ldf(bias, nb * 16 + m16, f32);
#pragma unroll
        for (int r = 0; r < 4; ++r)
          st[(mb * 16 + kb * 4 + r) * 64 + nb * 16 + m16] =
              f2h(acc[mb][nb][r] + bsv);
      }
    u16* gp = (u16*)out_ + (size_t)rowbase * 64;
    for (int i = lane; i < 512; i += 64)        // 512 x 16B = 8KB
      *(uint4*)(gp + i * 8) = *(const uint4*)&st[i * 8];
  } else if constexpr (L == 2) {
    // C-tile (80x128) -> dead slab (stride PSTH) in two 64-col passes,
    // maxpool over 20 rows each pass, write x1 fp16
    u16* st = myslab;
    const int pbase = tile * 16 + wv * 4;       // 4 points per wave
#pragma unroll
    for (int h = 0; h < 2; ++h) {
#pragma unroll
      for (int mb = 0; mb < MB; ++mb)
#pragma unroll
        for (int nb4 = 0; nb4 < 4; ++nb4) {
          const int nb = h * 4 + nb4;
          const float bsv = ldf(bias, ncol0 + nb * 16 + m16, f32);
#pragma unroll
          for (int r = 0; r < 4; ++r)
            st[(mb * 16 + kb * 4 + r) * PSTH + nb4 * 16 + m16] =
                f2h(acc[mb][nb][r] + bsv);
        }
#pragma unroll
      for (int j = 0; j < 4; ++j) {
        float m = -3.0e38f;
#pragma unroll
        for (int k = 0; k < 20; ++k)
          m = fmaxf(m, h2f(st[(j * 20 + k) * PSTH + lane]));
        ((u16*)out_)[(size_t)(pbase + j) * 128 + ncol0 + h * 64 + lane] = f2h(m);
      }
    }
  } else {
    // in-register max/sum over 32 rows + kb butterfly -> pmax/psum partials
    const int chunk = rowbase >> 5;
#pragma unroll
    for (int nb = 0; nb < NB; ++nb) {
      const int col = ncol0 + nb * 16 + m16;
      const float bsv = ldf(bias, col, f32);
      float m = -3.0e38f, s = 0.f;
#pragma unroll
      for (int mb = 0; mb < MB; ++mb)
#pragma unroll
        for (int r = 0; r < 4; ++r) {
          const float v = acc[mb][nb][r] + bsv;
          m = fmaxf(m, v); s += v;
        }
#pragma unroll
      for (int off = 16; off <= 32; off <<= 1) {
        m = fmaxf(m, __shfl_xor(m, off, 64));
        s += __shfl_xor(s, off, 64);
      }
      if (kb == 0) {
        pmax[(size_t)chunk * 1024 + col] = m;
        psum[(size_t)chunk * 1024 + col] = s;
      }
    }
  }
}

// ---------------- layer 4 partials (seg reduce fused in) --------------------
// c4t GLOBAL layout (angle-major): window w section-1 (g1..4 quads) at
// o*38400 + w*2048 ; g5 tail at o*38400 + 30720 + w*512.
// grid (15,8,2): z splits the 6 dot slices into 2x3 (240 blocks).
__global__ __launch_bounds__(256) void l4_kernel(const float* __restrict__ pmax,
                                                 const float* __restrict__ psum,
                                                 const float* __restrict__ c4t,
                                                 float* __restrict__ part) {
  __shared__ float F[2560];
  const int t = threadIdx.x;
  const int w = blockIdx.x, b = blockIdx.y, z = blockIdx.z;
  // fused segment combine (same reduce order as former seg2)
  const int ch = w * 128 + t;
  float xv;
  if (ch < 1024) {
    float m = -3.0e38f;
    for (int rc = 0; rc < 32; ++rc)
      m = fmaxf(m, pmax[(size_t)(b * 32 + rc) * 1024 + ch]);
    xv = m;
  } else {
    const int cc = ch - 1024;
    float s = 0.f;
    for (int rc = 0; rc < 32; ++rc)
      s += psum[(size_t)(b * 32 + rc) * 1024 + cc];
    xv = s * (1.0f / 1024.0f);
  }
  const float hm = 0.54f - 0.46f * cospif(2.0f * (float)t / 255.0f);
  const float aa = xv * hm;
  const float c1 = __cosf(aa), s1 = __sinf(aa);
  const float tc = 2.0f * c1;
  const float c2 = tc * c1 - 1.0f, s2 = tc * s1;
  const float c3 = tc * c2 - c1,   s3 = tc * s2 - s1;
  const float c4 = tc * c3 - c2,   s4 = tc * s3 - s2;
  const float a5 = aa * 5.0f;
  F[t * 8]     = c1; F[t * 8 + 1] = s1;
  F[t * 8 + 2] = c2; F[t * 8 + 3] = s2;
  F[t * 8 + 4] = c3; F[t * 8 + 5] = s3;
  F[t * 8 + 6] = c4; F[t * 8 + 7] = s4;
  F[2048 + t * 2]     = __cosf(a5);
  F[2048 + t * 2 + 1] = __sinf(a5);
  __syncthreads();
  if (t < 120) {
    const int o = t % 40, sl = t / 40;          // sl in [0,3)
    const int s = z * 3 + sl;                   // s in [0,6)
    const int f0 = s * 432;
    const int f1 = (f0 + 432 < 2560) ? (f0 + 432) : 2560;
    const float* cp1 = c4t + (size_t)o * 38400 + w * 2048;          // sec 1
    const float* cp2 = c4t + (size_t)o * 38400 + 30720 + w * 512;   // g5 tail
    float acc = 0.f;
    for (int f = f0; f < f1; f += 4) {   // 2048 boundary is float4-aligned
      const float* cpf = (f < 2048) ? (cp1 + f) : (cp2 + (f - 2048));
      const float4 cv = *(const float4*)cpf;
      const float4 fa = *(const float4*)&F[f];
      acc += fa.x * cv.x + fa.y * cv.y + fa.z * cv.z + fa.w * cv.w;
    }
    part[((b * 15 + w) * 6 + s) * 40 + o] = acc;
  }
}

__global__ void outred_kernel(const float* __restrict__ part,
                              const void* __restrict__ b4,
                              const void* __restrict__ pos,
                              void* __restrict__ outp) {
  int t = threadIdx.x;
  const bool f32 = wave_detect(pos);
  if (t >= 320) return;
  int b = t / 40, o = t % 40;
  float s = ldf(b4, o, f32);
  for (int w = 0; w < 15; ++w)
#pragma unroll
    for (int sl = 0; sl < 6; ++sl)
      s += part[((b * 15 + w) * 6 + sl) * 40 + o];
  if (f32) ((float*)outp)[t] = s;
  else     ((u16*)outp)[t] = f2bfr(s);
}

// ---------------------------------------------------------------------------
extern "C" void kernel_launch(void* const* d_in, const int* in_sizes, int n_in,
                              void* d_out, int out_size, void* d_ws,
                              size_t ws_size, hipStream_t stream) {
  (void)in_sizes; (void)n_in; (void)out_size; (void)ws_size;
  const void* pos = d_in[0];
  // d_in[1] = batch (int32) -- clouds are sorted equal-size, used implicitly
  const void* c1 = d_in[2];
  const void* b1 = d_in[3];
  const void* c2 = d_in[4];
  const void* b2 = d_in[5];
  const void* c3 = d_in[6];
  const void* b3 = d_in[7];
  const void* c4 = d_in[8];
  const void* b4 = d_in[9];

  char* ws = (char*)d_ws;
  int* nbr   = (int*)(ws + NBR_OFF);
  float* l4p = (float*)(ws + L4P_OFF);
  u16* c1t   = (u16*)(ws + C1T_OFF);
  u16* c2t   = (u16*)(ws + C2T_OFF);
  u16* c3t   = (u16*)(ws + C3T_OFF);
  float* c4t = (float*)(ws + C4T_OFF);
  float* pmax = (float*)(ws + PMAX_OFF);
  float* psum = (float*)(ws + PSUM_OFF);
  u16* x1    = (u16*)(ws + X1_OFF);
  u16* h1    = (u16*)(ws + H1_OFF);

  // merged prep: knn (blocks [0,2048)) + coeff transpose ([2048,17584))
  prep_kernel<<<17584, 256, 0, stream>>>(pos, nbr, c1, c1t, c2, c2t,
                                         c3, c3t, c4, c4t);

  // L1: 640 blocks x 256 rows, NT=DOUT=64
  kan_kernel<1><<<640, 256, 0, stream>>>(nullptr, nbr, pos, c1t, b1, h1,
                                         nullptr, nullptr);
  // L2 fused maxpool: 512 blocks x 320 rows (16 points), NT=128 single-pass
  kan_kernel<2><<<dim3(512), 256, 0, stream>>>(h1, nullptr, pos, c2t,
                                               b2, x1, nullptr, nullptr);
  // L3 fused segment partials: 1024 linear blocks, XCD-swizzled inside
  kan_kernel<3><<<1024, 256, 0, stream>>>(x1, nullptr, pos, c3t,
                                          b3, nullptr, pmax, psum);

  l4_kernel<<<dim3(15, 8, 2), 256, 0, stream>>>(pmax, psum, c4t, l4p);
  outred_kernel<<<1, 320, 0, stream>>>(l4p, b4, pos, d_out);
}

// Round 12
// 278.349 us; speedup vs baseline: 1.4783x; 1.0237x over previous
//
#include <hip/hip_runtime.h>

// ---------------------------------------------------------------------------
// STFT-Fourier-KAN DGCNN on MI355X.
// R30 (293.5): l4 z-split. R31 (284.9, best): detect deleted (per-wave
// ballot), knn+tkan merged into prep_kernel -- boundary model (~10us/launch)
// validated twice. kan<2>~78 / kan<3>~80 plateau structural (5 levers).
// R32: fuse kan<1> INTO kan<2>. A kan<2> wave's slab is exactly 80 rows x
// 64 cols of h1 -> embedded L1 phase computes it in-place: acc1[5][4]
// (NCH=2, af via the proven L1 pos/nbr path at MB=5, B direct from c1t --
// 8KB, L1-cache-resident), writes acc1+b1 to slab with the proven C-layout
// transform. Deletes the kan<1> launch + boundary + h1 21MB roundtrip.
// Order per wave: tables -> c2t Bbuf prologue -> barrier -> L1 phase
// (wave-private slab write) -> main loop (same-wave LDS RAW). acc1 dies
// before main acc inits (no pressure overlap). kan<3>/prep/l4/outred
// unchanged.
// ---------------------------------------------------------------------------

typedef unsigned short u16;
typedef unsigned int   u32;
typedef unsigned long long u64;
typedef __attribute__((ext_vector_type(8))) _Float16 half8;
typedef __attribute__((ext_vector_type(4))) float f32x4;

__device__ __forceinline__ float bf2f(u16 u) {
  u32 v = ((u32)u) << 16;
  return __uint_as_float(v);
}
__device__ __forceinline__ u16 f2bfr(float f) {  // bf16 round-to-nearest-even
  u32 x = __float_as_uint(f);
  u32 r = x + 0x7FFFu + ((x >> 16) & 1u);
  return (u16)(r >> 16);
}
__device__ __forceinline__ u16 f2h(float f) {    // fp16 RTN bits
  _Float16 h = (_Float16)f;
  u16 r;
  __builtin_memcpy(&r, &h, 2);
  return r;
}
__device__ __forceinline__ float h2f(u16 u) {
  _Float16 h;
  __builtin_memcpy(&h, &u, 2);
  return (float)h;
}
// dtype-dispatched external load (flag wave-uniform -> scalar branch)
__device__ __forceinline__ float ldf(const void* p, size_t i, bool f32) {
  return f32 ? ((const float*)p)[i] : bf2f(((const u16*)p)[i]);
}
__device__ __forceinline__ u64 minu64(u64 a, u64 b) { return a < b ? a : b; }

// per-wave dtype detect: every wave reads pos[0..63] as f32 and ballots the
// "plausible float" test -- wave-uniform result, no global flag roundtrip.
__device__ __forceinline__ bool wave_detect(const void* pos) {
  float a = fabsf(((const float*)pos)[threadIdx.x & 63]);
  bool ok = (a > 1.0e-3f && a < 100.0f);
  unsigned long long m = __ballot(ok);
  return __popcll(m) >= 32;
}

// ---------------- workspace layout (bytes) ----------------
#define NBR_OFF   ((size_t)0)                       // int32 [163840]       655,360
#define L4P_OFF   (((size_t)(1u << 20)) + 131072)   // f32 [8][15][240]     115,200
#define C1T_OFF   (((size_t)(1u << 20)) + 524288)   // fp16 [64][64]          8,192
#define C2T_OFF   (((size_t)(1u << 20)) + 589824)   // fp16 [128][1120]     286,720
#define C3T_OFF   ((size_t)(2u << 20))              // fp16 [1024][2240]  4,587,520
#define C4T_OFF   ((size_t)(7u << 20))              // f32  [40][38400]   6,144,000
#define PMAX_OFF  ((size_t)(13u << 20))             // f32 [256][1024]    1,048,576
#define PSUM_OFF  ((size_t)(14u << 20))             // f32 [256][1024]    1,048,576
#define X1_OFF    ((size_t)(15u << 20))             // fp16 [8192][128]   2,097,152
// peak ~17 MB (h1 eliminated)

// ---------------- tkan transpose body (compile-time constants) --------------
// Angle-major k-order: p < 4*NA: aa=p>>2, g=(p&3)+1 ; p in [4*NA,5*NA):
// aa=p-4*NA, g=5. f = 2*p + part. Pad f>=Kt with zeros.
template <int DOUT, int NW, int WW, int KPAD, int OUTF32>
__device__ __forceinline__ void tkan_body(const void* __restrict__ src,
                                          void* __restrict__ dst,
                                          int id, bool f32) {
  constexpr int NA = NW * WW;
  constexpr int Kt = NA * 10;
  constexpr int OS = NA * 5;
  const int o = id / KPAD, f = id % KPAD;   // literal KPAD -> magic multiply
  float v = 0.f;
  if (f < Kt) {
    const int part = f & 1, p = f >> 1;
    int aa, gg;
    if (p < 4 * NA) { aa = p >> 2;      gg = p & 3; }
    else            { aa = p - 4 * NA;  gg = 4;     }
    const int i = aa % WW, w = aa / WW;     // literal WW
    size_t sidx = (size_t)part * (DOUT * OS) + (size_t)o * OS +
                  (size_t)w * (WW * 5) + i * 5 + gg;
    v = ldf(src, sidx, f32);
  }
  if (OUTF32) ((float*)dst)[id] = v;
  else        ((u16*)dst)[id] = f2h(v);
}

// ---------------- merged prep: knn [0,2048) + coeff transpose [2048,17584) --
__global__ __launch_bounds__(256) void prep_kernel(
    const void* __restrict__ pos, int* __restrict__ nbr,
    const void* __restrict__ s1, void* __restrict__ d1,
    const void* __restrict__ s2, void* __restrict__ d2,
    const void* __restrict__ s3, void* __restrict__ d3,
    const void* __restrict__ s4, void* __restrict__ d4) {
  __shared__ float px[1024], py[1024], pz[1024];
  const bool f32 = wave_detect(pos);
  const int blk = blockIdx.x;
  const int t = threadIdx.x;

  if (blk >= 2048) {                         // ---- coeff transpose part ----
    const int tb = blk - 2048;
    if (tb < 16) {
      tkan_body<64, 2, 3, 64, 0>(s1, d1, tb * 256 + t, f32);
    } else if (tb < 576) {
      tkan_body<128, 7, 16, 1120, 0>(s2, d2, (tb - 16) * 256 + t, f32);
    } else if (tb < 9536) {
      tkan_body<1024, 7, 32, 2240, 0>(s3, d3, (tb - 576) * 256 + t, f32);
    } else {
      tkan_body<40, 15, 256, 38400, 1>(s4, d4, (tb - 9536) * 256 + t, f32);
    }
    return;
  }

  // ---- brute-force kNN: one wave per query ----
  const int b = blk >> 8;                    // cloud [0,8)
  const int x = blk & 255;                   // query group [0,256)
  const int base = b << 10;
  for (int j = t; j < 1024; j += 256) {
    size_t pidx = (size_t)(base + j) * 3;
    px[j] = ldf(pos, pidx, f32);
    py[j] = ldf(pos, pidx + 1, f32);
    pz[j] = ldf(pos, pidx + 2, f32);
  }
  __syncthreads();
  const int wv = t >> 6, lane = t & 63;
  const int q = x * 4 + wv;
  const float qx = px[q], qy = py[q], qz = pz[q];
  u64 key[16];
#pragma unroll
  for (int s = 0; s < 16; ++s) {
    const int j = s * 64 + lane;
    float dx = qx - px[j], dy = qy - py[j], dz = qz - pz[j];
    float d = __fadd_rn(__fadd_rn(__fmul_rn(dx, dx), __fmul_rn(dy, dy)),
                        __fmul_rn(dz, dz));
    key[s] = (j == q) ? ~0ull
                      : ((((u64)__float_as_uint(d)) << 32) | (u32)j);
  }
  const int obase = (base + q) * 20;
  for (int k = 0; k < 20; ++k) {
    u64 m = key[0];
#pragma unroll
    for (int s = 1; s < 16; ++s) m = minu64(m, key[s]);
#pragma unroll
    for (int off = 32; off >= 1; off >>= 1) {
      u32 lo = (u32)m, hi = (u32)(m >> 32);
      lo = __shfl_xor(lo, off, 64);
      hi = __shfl_xor(hi, off, 64);
      m = minu64(m, (((u64)hi) << 32) | lo);
    }
    if (lane == 0) nbr[obase + k] = (int)(u32)m;
#pragma unroll
    for (int s = 0; s < 16; ++s)
      if (key[s] == m) key[s] = ~0ull;  // idx embedded -> unique, safe
  }
}

// ---------------- MFMA KAN layer, LDS double-buffered B ---------------------
// L==2 additionally embeds the L1 layer: each wave computes its 80 slab rows
// of h1 in-place (acc1[5][4], NCH1=2, B direct from 8KB L1-resident c1t).
// Per chunk: 256 threads each load NPC 16B pieces of next chunk's B, build
// NEXT chunk's A fragments (pipelined one ahead), MFMA current chunk from
// Bbuf ds_read_b128 + last iter's af, then ds_write+barrier.
// PSTH=DIN+4 halves: lane stride -> 16 distinct banks.
template <int L>
__global__ __launch_bounds__(256, (L == 2) ? 2 : 3) void kan_kernel(
    const void* __restrict__ in_, const int* __restrict__ nbr,
    const void* __restrict__ pos, const u16* __restrict__ ct,
    const void* __restrict__ bias, void* __restrict__ out_,
    float* __restrict__ pmax, float* __restrict__ psum,
    const u16* __restrict__ ct1, const void* __restrict__ bias1) {
  constexpr int W    = (L == 2) ? 16  : 32;
  constexpr int S    = (L == 2) ? 8   : 16;
  constexpr int DIN  = (L == 2) ? 64  : 128;
  constexpr int NT   = (L == 2) ? 128 : 64;         // L2: full 128-col tile
  constexpr int NW   = (DIN - W) / S + 1;
  constexpr int NA   = NW * W;                      // angles
  constexpr int NPAIR = NA * 5;
  constexpr int S1P  = NA * 4;                      // section-1 pairs (g=1..4)
  constexpr int KROW  = NPAIR * 2;                  // ct row stride
  constexpr int NCH   = KROW / 32;                  // L2:35(odd!)  L3:70
  constexpr int NB    = NT / 16;                    // 8 or 4
  constexpr int RW    = (L == 2) ? 80 : 32;         // rows per wave
  constexpr int MB    = RW / 16;
  constexpr int PSTH  = DIN + 4;                    // slab stride (halves)
  constexpr int LGW   = (W == 16) ? 4 : 5;          // log2(W)
  constexpr int BCS   = NT * 8 + 8;                 // Bbuf halves per part
  constexpr int BBS   = 4 * BCS;                    // Bbuf halves per buffer
  constexpr int NPC   = NT / 64;                    // 16B B-pieces per thread

  __shared__ float hamS[W];
  __shared__ float wT1[(L == 2) ? 32 : 1];          // embedded-L1 tables
  __shared__ int   hT1[(L == 2) ? 32 : 1];
  __shared__ u16   slab[4 * RW * PSTH];
  __shared__ u16   Bbuf[2 * BBS];                   // [buf][part(4)][BCS]

  const bool f32 = wave_detect(pos);
  const u16* inH = (const u16*)in_;
  const int t = threadIdx.x;
  if (t < W) hamS[t] = 0.54f - 0.46f * cospif(2.0f * (float)t / (float)(W - 1));
  if constexpr (L == 2) {
    // embedded-L1 angle tables (W1=3, NPAIR1=30, S1P1=24)
    if (t < 32) {
      float wv_ = 0.f; int hx = 0;
      if (t < 30) {
        int aa, gg;
        if (t < 24) { aa = t >> 2;  gg = t & 3; }
        else        { aa = t - 24;  gg = 4;     }
        int i = aa % 3;
        float hm = 0.54f - 0.46f * cospif((float)i);   // 2*i/(3-1) = i
        wv_ = hm * (float)(gg + 1);
        hx = aa;
      }
      wT1[t] = wv_; hT1[t] = hx;
    }
  }

  // ---- block index: L3 uses XCD-aware swizzle (id%8-equal share 2 slices) --
  int tile, ncol0;
  if constexpr (L == 3) {
    const int id = blockIdx.x;                      // 1024 linear
    tile = (id >> 3) & 63;
    ncol0 = ((((id & 7) << 1) | (id >> 9))) * NT;
  } else {
    tile = blockIdx.x;
    ncol0 = 0;
  }
  const int lane = t & 63, wv = t >> 6;
  const int m16 = lane & 15, kb = lane >> 4;
  const int rowbase = tile * (4 * RW) + wv * RW;
  u16* myslab = &slab[wv * RW * PSTH];

  // B staging indices: piece p covers col=p>>2, part=p&3 (16B each)
  const u16* srcB[NPC];
  int sdst[NPC];
#pragma unroll
  for (int p_ = 0; p_ < NPC; ++p_) {
    const int pid = t + p_ * 256;
    const int scol = pid >> 2, spart = pid & 3;
    srcB[p_] = ct + (size_t)(ncol0 + scol) * KROW + spart * 8;
    sdst[p_] = spart * BCS + scol * 8;
  }

  // ---- stage wave-private fp16 slab from global input (L3 only) ----
  if constexpr (L == 3) {
    constexpr int F4R = DIN / 4;
    constexpr int TOT = RW * F4R;
    for (int i = lane; i < TOT; i += 64) {
      const int r = i / F4R, c4 = i % F4R;
      *(uint2*)(myslab + r * PSTH + c4 * 4) =
          *(const uint2*)(inH + (size_t)(rowbase + r) * DIN + c4 * 4);
    }
  }

  // ---- prologue: stage B chunk 0 ----
#pragma unroll
  for (int p_ = 0; p_ < NPC; ++p_) {
    const uint4 v = *(const uint4*)srcB[p_];
    *(uint4*)(Bbuf + sdst[p_]) = v;
  }
  __syncthreads();  // covers hamS/wT1/hT1 + Bbuf[0]

  // ---- embedded L1 phase (L==2): compute this wave's 80 slab rows of h1 ---
  if constexpr (L == 2) {
    f32x4 acc1[5][4];
#pragma unroll
    for (int mb = 0; mb < 5; ++mb)
#pragma unroll
      for (int nb = 0; nb < 4; ++nb) {
        acc1[mb][nb][0] = 0.f; acc1[mb][nb][1] = 0.f;
        acc1[mb][nb][2] = 0.f; acc1[mb][nb][3] = 0.f;
      }
#pragma unroll
    for (int c = 0; c < 2; ++c) {            // NCH1 = 2 (K padded 60->64)
      const int pg0 = c * 16 + kb * 4;
      float wm[4]; int hx[4]; bool val[4];
#pragma unroll
      for (int u = 0; u < 4; ++u) {
        const int pg = pg0 + u;
        wm[u] = wT1[pg]; hx[u] = hT1[pg]; val[u] = (pg < 30);
      }
      half8 af1[5];
#pragma unroll
      for (int mb = 0; mb < 5; ++mb) {
        const int row = rowbase + mb * 16 + m16;
        const int pt = row / 20;
        const int cloud = pt >> 10, ci = pt & 1023;
        const int cb = cloud << 10;
        const int jl = nbr[row];
#pragma unroll
        for (int u = 0; u < 4; ++u) {
          float cs = 0.f, sn = 0.f;
          if (val[u]) {
            const int aa = hx[u];
            float v;
            if (aa < 3) {
              v = ldf(pos, (size_t)(cb + ci) * 3 + aa, f32);
            } else {
              const int cc2 = aa - 3;
              v = ldf(pos, (size_t)(cb + jl) * 3 + cc2, f32) -
                  ldf(pos, (size_t)(cb + ci) * 3 + cc2, f32);
            }
            const float ang = v * wm[u];
            cs = __cosf(ang); sn = __sinf(ang);
          }
          af1[mb][2 * u]     = (_Float16)cs;
          af1[mb][2 * u + 1] = (_Float16)sn;
        }
      }
      // B direct from c1t [64 cols][64 k] -- 8KB, L1-cache-resident
#pragma unroll
      for (int nb = 0; nb < 4; ++nb) {
        const half8 bv = *(const half8*)(ct1 + (nb * 16 + m16) * 64 +
                                         c * 32 + kb * 8);
#pragma unroll
        for (int mb = 0; mb < 5; ++mb)
          acc1[mb][nb] = __builtin_amdgcn_mfma_f32_16x16x32_f16(
              af1[mb], bv, acc1[mb][nb], 0, 0, 0);
      }
    }
    // write h1 rows into wave-private slab (proven C-layout transform)
#pragma unroll
    for (int mb = 0; mb < 5; ++mb)
#pragma unroll
      for (int nb = 0; nb < 4; ++nb) {
        const float bsv = ldf(bias1, nb * 16 + m16, f32);
#pragma unroll
        for (int r = 0; r < 4; ++r)
          myslab[(mb * 16 + kb * 4 + r) * PSTH + nb * 16 + m16] =
              f2h(acc1[mb][nb][r] + bsv);
      }
    // same-wave LDS RAW below (compiler orders); no barrier needed
  }

  f32x4 acc[MB][NB];
#pragma unroll
  for (int mb = 0; mb < MB; ++mb)
#pragma unroll
    for (int nb = 0; nb < NB; ++nb) {
      acc[mb][nb][0] = 0.f; acc[mb][nb][1] = 0.f;
      acc[mb][nb][2] = 0.f; acc[mb][nb][3] = 0.f;
    }

  // ---- A-fragment builder for chunk c (reads slab only) ----
  auto build_af = [&](int c, half8* af) {
    const int pg0 = c * 16 + kb * 4;
    if (pg0 < S1P) {
      // section 1: one angle, g=1..4 -> Chebyshev recurrence
      const int aa = pg0 >> 2;
      const int i = aa & (W - 1), w = aa >> LGW;
      const int hidx = S * w + i;
      const float hm = hamS[i];
#pragma unroll
      for (int mb = 0; mb < MB; ++mb) {
        const u16* rp = myslab + (mb * 16 + m16) * PSTH;
        const float th = h2f(rp[hidx]) * hm;
        const float c1 = __cosf(th), s1 = __sinf(th);
        const float tc = 2.0f * c1;
        const float c2 = tc * c1 - 1.0f, s2 = tc * s1;
        const float c3 = tc * c2 - c1,   s3 = tc * s2 - s1;
        const float c4 = tc * c3 - c2,   s4 = tc * s3 - s2;
        af[mb][0] = (_Float16)c1; af[mb][1] = (_Float16)s1;
        af[mb][2] = (_Float16)c2; af[mb][3] = (_Float16)s2;
        af[mb][4] = (_Float16)c3; af[mb][5] = (_Float16)s3;
        af[mb][6] = (_Float16)c4; af[mb][7] = (_Float16)s4;
      }
    } else {
      // section 2: g=5 tail, 4 distinct angles, direct cos/sin
      const int q0 = pg0 - S1P;
      float wm[4]; int hx[4];
#pragma unroll
      for (int u = 0; u < 4; ++u) {
        const int aa = q0 + u;
        const int i = aa & (W - 1), w = aa >> LGW;
        hx[u] = S * w + i;
        wm[u] = hamS[i] * 5.0f;
      }
#pragma unroll
      for (int mb = 0; mb < MB; ++mb) {
        const u16* rp = myslab + (mb * 16 + m16) * PSTH;
#pragma unroll
        for (int u = 0; u < 4; ++u) {
          const float ang = h2f(rp[hx[u]]) * wm[u];
          af[mb][2 * u]     = (_Float16)__cosf(ang);
          af[mb][2 * u + 1] = (_Float16)__sinf(ang);
        }
      }
    }
  };

  // ---- one pipelined chunk: uses afc (built last iter), builds afn ----
  auto step = [&](int c, half8* afc, half8* afn) {
    const bool havenext = (c + 1 < NCH);
    // issue next chunk's B global load (overlaps everything below)
    uint4 bnext[NPC];
    if (havenext) {
#pragma unroll
      for (int p_ = 0; p_ < NPC; ++p_)
        bnext[p_] = *(const uint4*)(srcB[p_] + (c + 1) * 32);
    }
    // build NEXT chunk's A fragments; MFMA below consumes afc from LAST
    // iter -> trans chain off the MFMA critical path
    if (havenext) build_af(c + 1, afn);
    // MFMA: bv loaded per-nb (keep live set small -- R24 spill lesson)
    const u16* bb = Bbuf + (c & 1) * BBS + kb * BCS;
#pragma unroll
    for (int nb = 0; nb < NB; ++nb) {
      const half8 bv = *(const half8*)(bb + (nb * 16 + m16) * 8);
#pragma unroll
      for (int mb = 0; mb < MB; ++mb)
        acc[mb][nb] = __builtin_amdgcn_mfma_f32_16x16x32_f16(
            afc[mb], bv, acc[mb][nb], 0, 0, 0);
    }
    // commit next chunk's B to LDS, barrier
    if (havenext) {
#pragma unroll
      for (int p_ = 0; p_ < NPC; ++p_)
        *(uint4*)(Bbuf + ((c + 1) & 1) * BBS + sdst[p_]) = bnext[p_];
      __syncthreads();
    }
  };

  half8 afA[MB], afB[MB];
  build_af(0, afA);
  constexpr int NCH2 = (NCH / 2) * 2;  // even part: L2 34, L3 70
  for (int c = 0; c < NCH2; c += 2) {
    step(c, afA, afB);
    step(c + 1, afB, afA);
  }
  if constexpr ((NCH & 1) != 0) {
    // odd tail (L2: c=34). step(NCH2-1, afB, afA) built afA=af(NCH-1);
    // buf[(NCH-1)&1] was committed+barriered there. Consume it.
    step(NCH - 1, afA, afB);
  }

  // ---- fused epilogues (C layout: row=kb*4+r, col=m16 within 16x16) ----
  if constexpr (L == 2) {
    // C-tile (80x128) -> dead slab (stride PSTH) in two 64-col passes,
    // maxpool over 20 rows each pass, write x1 fp16
    u16* st = myslab;
    const int pbase = tile * 16 + wv * 4;       // 4 points per wave
#pragma unroll
    for (int h = 0; h < 2; ++h) {
#pragma unroll
      for (int mb = 0; mb < MB; ++mb)
#pragma unroll
        for (int nb4 = 0; nb4 < 4; ++nb4) {
          const int nb = h * 4 + nb4;
          const float bsv = ldf(bias, nb * 16 + m16, f32);
#pragma unroll
          for (int r = 0; r < 4; ++r)
            st[(mb * 16 + kb * 4 + r) * PSTH + nb4 * 16 + m16] =
                f2h(acc[mb][nb][r] + bsv);
        }
#pragma unroll
      for (int j = 0; j < 4; ++j) {
        float m = -3.0e38f;
#pragma unroll
        for (int k = 0; k < 20; ++k)
          m = fmaxf(m, h2f(st[(j * 20 + k) * PSTH + lane]));
        ((u16*)out_)[(size_t)(pbase + j) * 128 + h * 64 + lane] = f2h(m);
      }
    }
  } else {
    // in-register max/sum over 32 rows + kb butterfly -> pmax/psum partials
    const int chunk = rowbase >> 5;
#pragma unroll
    for (int nb = 0; nb < NB; ++nb) {
      const int col = ncol0 + nb * 16 + m16;
      const float bsv = ldf(bias, col, f32);
      float m = -3.0e38f, s = 0.f;
#pragma unroll
      for (int mb = 0; mb < MB; ++mb)
#pragma unroll
        for (int r = 0; r < 4; ++r) {
          const float v = acc[mb][nb][r] + bsv;
          m = fmaxf(m, v); s += v;
        }
#pragma unroll
      for (int off = 16; off <= 32; off <<= 1) {
        m = fmaxf(m, __shfl_xor(m, off, 64));
        s += __shfl_xor(s, off, 64);
      }
      if (kb == 0) {
        pmax[(size_t)chunk * 1024 + col] = m;
        psum[(size_t)chunk * 1024 + col] = s;
      }
    }
  }
}

// ---------------- layer 4 partials (seg reduce fused in) --------------------
// c4t GLOBAL layout (angle-major): window w section-1 (g1..4 quads) at
// o*38400 + w*2048 ; g5 tail at o*38400 + 30720 + w*512.
// grid (15,8,2): z splits the 6 dot slices into 2x3 (240 blocks).
__global__ __launch_bounds__(256) void l4_kernel(const float* __restrict__ pmax,
                                                 const float* __restrict__ psum,
                                                 const float* __restrict__ c4t,
                                                 float* __restrict__ part) {
  __shared__ float F[2560];
  const int t = threadIdx.x;
  const int w = blockIdx.x, b = blockIdx.y, z = blockIdx.z;
  // fused segment combine (same reduce order as former seg2)
  const int ch = w * 128 + t;
  float xv;
  if (ch < 1024) {
    float m = -3.0e38f;
    for (int rc = 0; rc < 32; ++rc)
      m = fmaxf(m, pmax[(size_t)(b * 32 + rc) * 1024 + ch]);
    xv = m;
  } else {
    const int cc = ch - 1024;
    float s = 0.f;
    for (int rc = 0; rc < 32; ++rc)
      s += psum[(size_t)(b * 32 + rc) * 1024 + cc];
    xv = s * (1.0f / 1024.0f);
  }
  const float hm = 0.54f - 0.46f * cospif(2.0f * (float)t / 255.0f);
  const float aa = xv * hm;
  const float c1 = __cosf(aa), s1 = __sinf(aa);
  const float tc = 2.0f * c1;
  const float c2 = tc * c1 - 1.0f, s2 = tc * s1;
  const float c3 = tc * c2 - c1,   s3 = tc * s2 - s1;
  const float c4 = tc * c3 - c2,   s4 = tc * s3 - s2;
  const float a5 = aa * 5.0f;
  F[t * 8]     = c1; F[t * 8 + 1] = s1;
  F[t * 8 + 2] = c2; F[t * 8 + 3] = s2;
  F[t * 8 + 4] = c3; F[t * 8 + 5] = s3;
  F[t * 8 + 6] = c4; F[t * 8 + 7] = s4;
  F[2048 + t * 2]     = __cosf(a5);
  F[2048 + t * 2 + 1] = __sinf(a5);
  __syncthreads();
  if (t < 120) {
    const int o = t % 40, sl = t / 40;          // sl in [0,3)
    const int s = z * 3 + sl;                   // s in [0,6)
    const int f0 = s * 432;
    const int f1 = (f0 + 432 < 2560) ? (f0 + 432) : 2560;
    const float* cp1 = c4t + (size_t)o * 38400 + w * 2048;          // sec 1
    const float* cp2 = c4t + (size_t)o * 38400 + 30720 + w * 512;   // g5 tail
    float acc = 0.f;
    for (int f = f0; f < f1; f += 4) {   // 2048 boundary is float4-aligned
      const float* cpf = (f < 2048) ? (cp1 + f) : (cp2 + (f - 2048));
      const float4 cv = *(const float4*)cpf;
      const float4 fa = *(const float4*)&F[f];
      acc += fa.x * cv.x + fa.y * cv.y + fa.z * cv.z + fa.w * cv.w;
    }
    part[((b * 15 + w) * 6 + s) * 40 + o] = acc;
  }
}

__global__ void outred_kernel(const float* __restrict__ part,
                              const void* __restrict__ b4,
                              const void* __restrict__ pos,
                              void* __restrict__ outp) {
  int t = threadIdx.x;
  const bool f32 = wave_detect(pos);
  if (t >= 320) return;
  int b = t / 40, o = t % 40;
  float s = ldf(b4, o, f32);
  for (int w = 0; w < 15; ++w)
#pragma unroll
    for (int sl = 0; sl < 6; ++sl)
      s += part[((b * 15 + w) * 6 + sl) * 40 + o];
  if (f32) ((float*)outp)[t] = s;
  else     ((u16*)outp)[t] = f2bfr(s);
}

// ---------------------------------------------------------------------------
extern "C" void kernel_launch(void* const* d_in, const int* in_sizes, int n_in,
                              void* d_out, int out_size, void* d_ws,
                              size_t ws_size, hipStream_t stream) {
  (void)in_sizes; (void)n_in; (void)out_size; (void)ws_size;
  const void* pos = d_in[0];
  // d_in[1] = batch (int32) -- clouds are sorted equal-size, used implicitly
  const void* c1 = d_in[2];
  const void* b1 = d_in[3];
  const void* c2 = d_in[4];
  const void* b2 = d_in[5];
  const void* c3 = d_in[6];
  const void* b3 = d_in[7];
  const void* c4 = d_in[8];
  const void* b4 = d_in[9];

  char* ws = (char*)d_ws;
  int* nbr   = (int*)(ws + NBR_OFF);
  float* l4p = (float*)(ws + L4P_OFF);
  u16* c1t   = (u16*)(ws + C1T_OFF);
  u16* c2t   = (u16*)(ws + C2T_OFF);
  u16* c3t   = (u16*)(ws + C3T_OFF);
  float* c4t = (float*)(ws + C4T_OFF);
  float* pmax = (float*)(ws + PMAX_OFF);
  float* psum = (float*)(ws + PSUM_OFF);
  u16* x1    = (u16*)(ws + X1_OFF);

  // merged prep: knn (blocks [0,2048)) + coeff transpose ([2048,17584))
  prep_kernel<<<17584, 256, 0, stream>>>(pos, nbr, c1, c1t, c2, c2t,
                                         c3, c3t, c4, c4t);

  // L1+L2 fused: 512 blocks x 320 rows; each wave computes its 80 h1 rows
  // in-slab (embedded L1) then runs the NT=128 L2 + maxpool
  kan_kernel<2><<<dim3(512), 256, 0, stream>>>(nullptr, nbr, pos, c2t,
                                               b2, x1, nullptr, nullptr,
                                               c1t, b1);
  // L3 fused segment partials: 1024 linear blocks, XCD-swizzled inside
  kan_kernel<3><<<1024, 256, 0, stream>>>(x1, nullptr, pos, c3t,
                                          b3, nullptr, pmax, psum,
                                          nullptr, nullptr);

  l4_kernel<<<dim3(15, 8, 2), 256, 0, stream>>>(pmax, psum, c4t, l4p);
  outred_kernel<<<1, 320, 0, stream>>>(l4p, b4, pos, d_out);
}